// Round 12
// baseline (3352.956 us; speedup 1.0000x reference)
//
#include <hip/hip_runtime.h>

#define NB    8
#define NPTS  16384
#define NS    512
#define NK    64
#define C1    64
#define C2    128
#define RAD2  0.25f
#define MTOT  (NB*NS*NK)   // 262144 rows
// ws layout: feat (6.29MB) | stats (768 f) | slots (8*512*32 u64 = 1MB)
// stats: [0:64) s0sum | [64:128) s0sq | [128:256) s1sum | [256:384) s1sq
// [384:448) bn0a | [448:512) bn0c | [512:640) bn1a | [640:768) bn1c

typedef __bf16 bfv8 __attribute__((ext_vector_type(8)));   // MFMA A/B fragment
typedef float f32x4 __attribute__((ext_vector_type(4)));

extern __shared__ char dynsmem[];   // single TU-wide dynamic-LDS symbol

// u32 max reduce step via DPP (positive floats compare as u32).
#define UMAX_DPP(x, CTRL, RM)                                                   \
    do {                                                                        \
        unsigned _m = (unsigned)__builtin_amdgcn_update_dpp((int)(x), (int)(x), \
                                                            CTRL, RM, 0xf, false); \
        x = (x > _m) ? x : _m;                                                  \
    } while (0)

// ---------------- FPS: multi-block, device-scope sync ----------------
// 32 blocks/batch x 512 threads, 1 point/thread (coords+dd in 4 VGPRs; zero
// LDS reads in scan). Per iter: wave DPP value-max + ballot min-idx ->
// block reduce -> release-store packed u64 (valbits<<32 | 0x7fffffff-idx;
// u64 max == max-val-then-min-idx, exact jnp.argmax tie-break) -> wave0
// acquire-polls 32 slots -> shfl u64 reduce -> winner coords from L2.
// Slots pre-zeroed each launch. Distance math bit-exact (__f*_rn, ((x+y)+z)).
__global__ __launch_bounds__(512) void fps_kernel(const float* __restrict__ xyz,
                                                  float* __restrict__ out,
                                                  unsigned long long* __restrict__ slots) {
    int gb = blockIdx.x;            // 0..255
    int b = gb >> 5;                // batch
    int blk = gb & 31;              // block within batch
    int tid = threadIdx.x;
    int lane = tid & 63;
    int w = tid >> 6;               // 0..7
    const float* base = xyz + (size_t)b * NPTS * 3;
    int p = (blk << 9) + tid;       // batch-local point index
    float px = base[p * 3 + 0], py = base[p * 3 + 1], pz = base[p * 3 + 2];
    float dd = 1e10f;
    __shared__ unsigned long long warr[8];
    __shared__ float sc[3];
    unsigned long long* bslots = slots + (size_t)b * NS * 32;
    float cx = base[0], cy = base[1], cz = base[2];
    if (blk == 0 && tid == 0) {
        float* o = out + (size_t)b * NS * 3;
        o[0] = cx; o[1] = cy; o[2] = cz;
    }
    for (int i = 1; i < NS; ++i) {
        // bit-exact: rn ops, no contraction, sum order ((x+y)+z)
        float dx = __fsub_rn(px, cx);
        float dy = __fsub_rn(py, cy);
        float dz = __fsub_rn(pz, cz);
        float d = __fadd_rn(__fadd_rn(__fmul_rn(dx, dx), __fmul_rn(dy, dy)),
                            __fmul_rn(dz, dz));
        dd = fminf(dd, d);
        // wave(64) value max via DPP; winner value lands in lane 63
        unsigned vb = __float_as_uint(dd);
        UMAX_DPP(vb, 0xB1, 0xf);   // quad_perm xor1
        UMAX_DPP(vb, 0x4E, 0xf);   // quad_perm xor2
        UMAX_DPP(vb, 0x141, 0xf);  // row_half_mirror
        UMAX_DPP(vb, 0x140, 0xf);  // row_mirror
        UMAX_DPP(vb, 0x142, 0xa);  // row_bcast15
        UMAX_DPP(vb, 0x143, 0xc);  // row_bcast31
        unsigned wmax = (unsigned)__builtin_amdgcn_readlane((int)vb, 63);
        unsigned long long mk = __ballot(__float_as_uint(dd) == wmax);
        if (lane == 0) {
            int ml = (int)(__ffsll(mk) - 1);              // min lane == min idx
            int idx = (blk << 9) + (w << 6) + ml;
            warr[w] = ((unsigned long long)wmax << 32) |
                      (unsigned)(0x7fffffff - idx);
        }
        __syncthreads();
        if (tid == 0) {
            unsigned long long bp = warr[0];
#pragma unroll
            for (int k = 1; k < 8; ++k) {
                unsigned long long v = warr[k];
                if (v > bp) bp = v;
            }
            __hip_atomic_store(&bslots[(size_t)i * 32 + blk], bp,
                               __ATOMIC_RELEASE, __HIP_MEMORY_SCOPE_AGENT);
        }
        if (w == 0) {
            // lanes 0-31 poll slots (lanes 32-63 duplicate -> full ballot)
            const unsigned long long* ps = &bslots[(size_t)i * 32 + (lane & 31)];
            unsigned long long v;
            do {
                v = __hip_atomic_load(ps, __ATOMIC_ACQUIRE,
                                      __HIP_MEMORY_SCOPE_AGENT);
            } while (!__all(v != 0ull));
            // u64 max reduce over the 32 candidates (dups harmless)
#pragma unroll
            for (int off = 1; off <= 16; off <<= 1) {
                unsigned long long o = __shfl_xor(v, off);
                if (o > v) v = o;
            }
            int idx = 0x7fffffff - (int)(unsigned)(v & 0xffffffffu);
            const float* cp = base + (size_t)idx * 3;
            if (lane < 3) {
                float c = cp[lane];
                sc[lane] = c;
                if (blk == 0) out[((size_t)b * NS + i) * 3 + lane] = c;
            }
        }
        __syncthreads();
        cx = sc[0]; cy = sc[1]; cz = sc[2];
    }
}

// ------------- Ball query (exact expanded-form distance) + gather -------------
__global__ __launch_bounds__(256) void ballq_kernel(const float* __restrict__ xyz,
                                                    const float* __restrict__ pts,
                                                    const float* __restrict__ newxyz,
                                                    float* __restrict__ feat) {
    int w = threadIdx.x >> 6;
    int lane = threadIdx.x & 63;
    int wid = blockIdx.x * 4 + w;   // 0..4095 == b*512+s
    int b = wid >> 9;
    const float* nx = newxyz + (size_t)wid * 3;
    float cx = nx[0], cy = nx[1], cz = nx[2];
    float sa = __fadd_rn(__fadd_rn(__fmul_rn(cx, cx), __fmul_rn(cy, cy)),
                         __fmul_rn(cz, cz));
    __shared__ int sidx[4][64];
    const float* base = xyz + (size_t)b * NPTS * 3;
    int cnt = 0;
    for (int off = 0; off < NPTS && cnt < NK; off += 64) {
        int p = off + lane;
        float bx = base[p * 3 + 0], by = base[p * 3 + 1], bz = base[p * 3 + 2];
        float sb = __fadd_rn(__fadd_rn(__fmul_rn(bx, bx), __fmul_rn(by, by)),
                             __fmul_rn(bz, bz));
        float dt = __fadd_rn(__fadd_rn(__fmul_rn(cx, bx), __fmul_rn(cy, by)),
                             __fmul_rn(cz, bz));
        float sq = __fsub_rn(__fadd_rn(sa, sb), __fmul_rn(2.0f, dt));
        bool inb = !(sq > RAD2);           // strict >, matches reference
        unsigned long long mask = __ballot(inb);
        int pos = cnt + (int)__popcll(mask & ((1ull << lane) - 1ull));
        if (inb && pos < NK) sidx[w][pos] = p;
        cnt += (int)__popcll(mask);
    }
    __syncthreads();
    int filled = cnt < NK ? cnt : NK;
    int sel = (lane < filled) ? lane : 0;
    int p = (filled > 0) ? sidx[w][sel] : 0;  // filled>0 always (self in radius)
    float gx = base[p * 3 + 0], gy = base[p * 3 + 1], gz = base[p * 3 + 2];
    const float* pb = pts + (size_t)b * NPTS * 3;
    float q0 = pb[p * 3 + 0], q1 = pb[p * 3 + 1], q2 = pb[p * 3 + 2];
    float* fr = feat + ((size_t)wid * NK + lane) * 6;
    fr[0] = __fsub_rn(gx, cx);
    fr[1] = __fsub_rn(gy, cy);
    fr[2] = __fsub_rn(gz, cz);
    fr[3] = q0; fr[4] = q1; fr[5] = q2;
}

// ---------------- Layer-0 stats: per-channel sum/sumsq of h0raw ----------------
__global__ __launch_bounds__(256) void stats0_kernel(const float* __restrict__ feat,
                                                     const float* __restrict__ W0,
                                                     const float* __restrict__ b0,
                                                     float* __restrict__ stats) {
    int lane = threadIdx.x & 63;
    int wid = blockIdx.x * 4 + (threadIdx.x >> 6);  // 0..1023
    float w0[6];
#pragma unroll
    for (int j = 0; j < 6; ++j) w0[j] = W0[lane * 6 + j];
    float bb = b0[lane];
    float ssum = 0.f, ssq = 0.f;
    int r0 = wid * 256;
    for (int r = r0; r < r0 + 256; ++r) {
        const float* f = feat + (size_t)r * 6;
        float h = bb;
#pragma unroll
        for (int j = 0; j < 6; ++j) h = fmaf(w0[j], f[j], h);
        ssum += h;
        ssq = fmaf(h, h, ssq);
    }
    atomicAdd(&stats[lane], ssum);
    atomicAdd(&stats[64 + lane], ssq);
}

__global__ void fin0_kernel(const float* __restrict__ g0, const float* __restrict__ be0,
                            float* __restrict__ stats) {
    int c = threadIdx.x;  // 64 threads
    const float inv = 1.0f / (float)MTOT;  // 2^-18, exact
    float mu = stats[c] * inv;
    float var = fmaxf(stats[64 + c] * inv - mu * mu, 0.f);
    float a = g0[c] * rsqrtf(var + 1e-5f);
    stats[384 + c] = a;
    stats[448 + c] = fmaf(-mu, a, be0[c]);
}

// ---------------- Layer-1 stats: recompute h0n -> h1raw, sum/sumsq ----------------
__global__ __launch_bounds__(256) void stats1_kernel(const float* __restrict__ feat,
                                                     const float* __restrict__ W0,
                                                     const float* __restrict__ b0,
                                                     const float* __restrict__ W1,
                                                     const float* __restrict__ b1,
                                                     float* __restrict__ stats) {
    int lane = threadIdx.x & 63;
    int w = threadIdx.x >> 6;
    int half = w & 1;
    int pairG = blockIdx.x * 2 + (w >> 1);  // 0..2047
    int ch = half * 64 + lane;
    float w0r[6];
#pragma unroll
    for (int j = 0; j < 6; ++j) w0r[j] = W0[lane * 6 + j];
    float b0v = b0[lane];
    float a0 = stats[384 + lane], c0 = stats[448 + lane];
    float w1r[64];
#pragma unroll
    for (int j = 0; j < 64; ++j) w1r[j] = W1[ch * 64 + j];
    float b1v = b1[ch];
    float ssum = 0.f, ssq = 0.f;
    int r0 = pairG * 128;
    for (int r = r0; r < r0 + 128; ++r) {
        const float* f = feat + (size_t)r * 6;
        float h = b0v;
#pragma unroll
        for (int j = 0; j < 6; ++j) h = fmaf(w0r[j], f[j], h);
        float h0n = fmaxf(fmaf(a0, h, c0), 0.f);
        int hbits = __float_as_int(h0n);
        float a0c = 0.f, a1c = 0.f, a2c = 0.f, a3c = 0.f;
#pragma unroll
        for (int j = 0; j < 64; j += 4) {
            a0c = fmaf(w1r[j + 0], __int_as_float(__builtin_amdgcn_readlane(hbits, j + 0)), a0c);
            a1c = fmaf(w1r[j + 1], __int_as_float(__builtin_amdgcn_readlane(hbits, j + 1)), a1c);
            a2c = fmaf(w1r[j + 2], __int_as_float(__builtin_amdgcn_readlane(hbits, j + 2)), a2c);
            a3c = fmaf(w1r[j + 3], __int_as_float(__builtin_amdgcn_readlane(hbits, j + 3)), a3c);
        }
        float acc = b1v + ((a0c + a1c) + (a2c + a3c));
        ssum += acc;
        ssq = fmaf(acc, acc, ssq);
    }
    atomicAdd(&stats[128 + ch], ssum);
    atomicAdd(&stats[256 + ch], ssq);
}

__global__ void fin1_kernel(const float* __restrict__ g1, const float* __restrict__ be1,
                            float* __restrict__ stats) {
    int c = threadIdx.x;  // 128 threads
    const float inv = 1.0f / (float)MTOT;
    float mu = stats[128 + c] * inv;
    float var = fmaxf(stats[256 + c] * inv - mu * mu, 0.f);
    float a = g1[c] * rsqrtf(var + 1e-5f);
    stats[512 + c] = a;
    stats[640 + c] = fmaf(-mu, a, be1[c]);
}

// ---------------- Final: MFMA bf16-split GEMM + BN + maxpool ----------------
__global__ __launch_bounds__(256) void final_mfma_kernel(const float* __restrict__ feat,
                                                         const float* __restrict__ W0,
                                                         const float* __restrict__ b0,
                                                         const float* __restrict__ W1,
                                                         const float* __restrict__ b1,
                                                         const float* __restrict__ stats,
                                                         float* __restrict__ out) {
    char* lds = dynsmem;
    // [0,16K) W1hi [128][64] bf16 swz | [16K,32K) W1lo | [32K+w*16K) X: hi 8K, lo 8K
    int tid = threadIdx.x;
    int lane = tid & 63;
    int w = tid >> 6;
    int g = blockIdx.x * 4 + w;  // 0..4095
    // --- stage W1 hi/lo (whole block) ---
    for (int idx = tid; idx < 8192; idx += 256) {
        int o = idx >> 6, c = idx & 63;
        float v = W1[idx];
        unsigned u = __float_as_uint(v);
        unsigned hi = (u + 0x7fffu + ((u >> 16) & 1u)) >> 16;
        float rem = v - __uint_as_float(hi << 16);
        unsigned ur = __float_as_uint(rem);
        unsigned lo = (ur + 0x7fffu + ((ur >> 16) & 1u)) >> 16;
        int byt = (c * 2) ^ ((o & 7) << 4);
        *(unsigned short*)(lds + o * 128 + byt) = (unsigned short)hi;
        *(unsigned short*)(lds + 16384 + o * 128 + byt) = (unsigned short)lo;
    }
    // --- phase 1: h0n (exact, same expression as stats1) -> split into LDS ---
    char* X = lds + 32768 + w * 16384;  // hi @0, lo @8192
    float w0r[6];
#pragma unroll
    for (int j = 0; j < 6; ++j) w0r[j] = W0[lane * 6 + j];
    float b0v = b0[lane];
    float a0 = stats[384 + lane], c0v = stats[448 + lane];
    __syncthreads();  // W1 staged
    const float* fb = feat + (size_t)g * 64 * 6;
#pragma unroll 4
    for (int r = 0; r < 64; ++r) {
        const float* f = fb + r * 6;
        float h = b0v;
#pragma unroll
        for (int j = 0; j < 6; ++j) h = fmaf(w0r[j], f[j], h);
        float hn = fmaxf(fmaf(a0, h, c0v), 0.f);
        unsigned u = __float_as_uint(hn);
        unsigned hi = (u + 0x7fffu + ((u >> 16) & 1u)) >> 16;
        float rem = hn - __uint_as_float(hi << 16);
        unsigned ur = __float_as_uint(rem);
        unsigned lo = (ur + 0x7fffu + ((ur >> 16) & 1u)) >> 16;
        int byt = (lane * 2) ^ ((r & 7) << 4);
        *(unsigned short*)(X + r * 128 + byt) = (unsigned short)hi;
        *(unsigned short*)(X + 8192 + r * 128 + byt) = (unsigned short)lo;
    }
    __syncthreads();  // X + W1 visible
    // --- BN1 params per tn tile (o = tn*16 + lane&15) ---
    float a1v[8], d1v[8];
#pragma unroll
    for (int tn = 0; tn < 8; ++tn) {
        int o = tn * 16 + (lane & 15);
        float a1 = stats[512 + o];
        a1v[tn] = a1;
        d1v[tn] = fmaf(a1, b1[o], stats[640 + o]);  // a1*b1 + c1
    }
    float mx[8];
#pragma unroll
    for (int tn = 0; tn < 8; ++tn) mx[tn] = -1e30f;
    // --- GEMM: tm outer (A loaded once), tn inner (B loaded in-loop) ---
#pragma unroll
    for (int tm = 0; tm < 4; ++tm) {
        bfv8 Ah[2], Al[2];
#pragma unroll
        for (int tk = 0; tk < 2; ++tk) {
            int r = tm * 16 + (lane & 15);
            int colb = (((lane >> 4) * 16) + tk * 64) ^ ((r & 7) << 4);
            Ah[tk] = *(const bfv8*)(X + r * 128 + colb);
            Al[tk] = *(const bfv8*)(X + 8192 + r * 128 + colb);
        }
#pragma unroll
        for (int tn = 0; tn < 8; ++tn) {
            int o = tn * 16 + (lane & 15);
            f32x4 acc = {0.f, 0.f, 0.f, 0.f};
#pragma unroll
            for (int tk = 0; tk < 2; ++tk) {
                int colb = (((lane >> 4) * 16) + tk * 64) ^ ((o & 7) << 4);
                bfv8 Bh = *(const bfv8*)(lds + o * 128 + colb);
                bfv8 Bl = *(const bfv8*)(lds + 16384 + o * 128 + colb);
                acc = __builtin_amdgcn_mfma_f32_16x16x32_bf16(Ah[tk], Bh, acc, 0, 0, 0);
                acc = __builtin_amdgcn_mfma_f32_16x16x32_bf16(Ah[tk], Bl, acc, 0, 0, 0);
                acc = __builtin_amdgcn_mfma_f32_16x16x32_bf16(Al[tk], Bh, acc, 0, 0, 0);
            }
            // epilogue: h1n = relu(a1*acc + (a1*b1 + c1)); max over the 4 rows
            float t0 = fmaxf(fmaf(a1v[tn], acc[0], d1v[tn]), 0.f);
            float t1 = fmaxf(fmaf(a1v[tn], acc[1], d1v[tn]), 0.f);
            float t2 = fmaxf(fmaf(a1v[tn], acc[2], d1v[tn]), 0.f);
            float t3 = fmaxf(fmaf(a1v[tn], acc[3], d1v[tn]), 0.f);
            mx[tn] = fmaxf(mx[tn], fmaxf(fmaxf(t0, t1), fmaxf(t2, t3)));
        }
    }
    // cross-lane max over row groups (lanes 16 apart hold other rows)
#pragma unroll
    for (int tn = 0; tn < 8; ++tn) {
        float v = mx[tn];
        v = fmaxf(v, __shfl_xor(v, 16));
        v = fmaxf(v, __shfl_xor(v, 32));
        mx[tn] = v;
    }
    if (lane < 16) {
        size_t ob = 12288 + (size_t)g * 128;
#pragma unroll
        for (int tn = 0; tn < 8; ++tn) out[ob + tn * 16 + lane] = mx[tn];
    }
}

extern "C" void kernel_launch(void* const* d_in, const int* in_sizes, int n_in,
                              void* d_out, int out_size, void* d_ws, size_t ws_size,
                              hipStream_t stream) {
    const float* xyz = (const float*)d_in[0];
    const float* pts = (const float*)d_in[1];
    const float* W0  = (const float*)d_in[2];
    const float* b0  = (const float*)d_in[3];
    const float* g0  = (const float*)d_in[4];
    const float* be0 = (const float*)d_in[5];
    const float* W1  = (const float*)d_in[6];
    const float* b1  = (const float*)d_in[7];
    const float* g1  = (const float*)d_in[8];
    const float* be1 = (const float*)d_in[9];
    float* out = (float*)d_out;

    float* feat  = (float*)d_ws;                     // 262144*6 floats = 6.29 MB
    float* stats = feat + (size_t)MTOT * 6;          // 768 floats
    unsigned long long* slots = (unsigned long long*)(stats + 768);  // 1 MB

    const int fm_lds = 98304;  // 32K W1 + 4x16K X
    (void)hipFuncSetAttribute(reinterpret_cast<const void*>(final_mfma_kernel),
                              hipFuncAttributeMaxDynamicSharedMemorySize, fm_lds);

    (void)hipMemsetAsync(stats, 0, 384 * sizeof(float), stream);
    (void)hipMemsetAsync(slots, 0, (size_t)NB * NS * 32 * 8, stream);
    fps_kernel<<<NB * 32, 512, 0, stream>>>(xyz, out, slots);
    ballq_kernel<<<1024, 256, 0, stream>>>(xyz, pts, out, feat);
    stats0_kernel<<<256, 256, 0, stream>>>(feat, W0, b0, stats);
    fin0_kernel<<<1, 64, 0, stream>>>(g0, be0, stats);
    stats1_kernel<<<1024, 256, 0, stream>>>(feat, W0, b0, W1, b1, stats);
    fin1_kernel<<<1, 128, 0, stream>>>(g1, be1, stats);
    final_mfma_kernel<<<1024, 256, fm_lds, stream>>>(feat, W0, b0, W1, b1, stats, out);
}

// Round 13
// 1063.736 us; speedup vs baseline: 3.1521x; 3.1521x over previous
//
#include <hip/hip_runtime.h>

#define NB    8
#define NPTS  16384
#define NS    512
#define NK    64
#define C1    64
#define C2    128
#define RAD2  0.25f
#define MTOT  (NB*NS*NK)   // 262144 rows
// ws: feat (6.29MB) | stats (768 f)
// stats: [0:64) s0sum | [64:128) s0sq | [128:256) s1sum | [256:384) s1sq

typedef float v2f __attribute__((ext_vector_type(2)));
typedef __bf16 bfv8 __attribute__((ext_vector_type(8)));   // MFMA A/B fragment
typedef float f32x4 __attribute__((ext_vector_type(4)));

extern __shared__ char dynsmem[];   // single TU-wide dynamic-LDS symbol

// u32 max/min reduce steps via DPP (positive floats compare as u32).
#define UMAX_DPP(x, CTRL, RM)                                                   \
    do {                                                                        \
        unsigned _m = (unsigned)__builtin_amdgcn_update_dpp((int)(x), (int)(x), \
                                                            CTRL, RM, 0xf, false); \
        x = (x > _m) ? x : _m;                                                  \
    } while (0)
#define UMIN_DPP(x, CTRL, RM)                                                   \
    do {                                                                        \
        unsigned _m = (unsigned)__builtin_amdgcn_update_dpp((int)(x), (int)(x), \
                                                            CTRL, RM, 0xf, false); \
        x = (x < _m) ? x : _m;                                                  \
    } while (0)

// ---------------- FPS: bit-exact farthest point sampling (r8, 811 us) -------
// 1024 threads x 16 points (8 float2 pairs). y/z planes in 128 KB dynamic
// LDS; px + dd in VGPRs. VALUE-ONLY scan (plain float2 ops, contract off ->
// bit-exact); wave+block u32-max DPP reduce -> exact block max W; index
// discovered by the wave(s) holding W (lowest flat idx == jnp.argmax);
// centroid via readfirstlane + L2 load; 2 barriers/iter.
__global__ __launch_bounds__(1024, 4) void fps_kernel(const float* __restrict__ xyz,
                                                      float* __restrict__ out) {
#pragma clang fp contract(off)
    int b = blockIdx.x;
    int tid = threadIdx.x;
    int lane = tid & 63;
    int w = tid >> 6;  // 16 waves
    const float* base = xyz + (size_t)b * NPTS * 3;
    v2f* yv = (v2f*)dynsmem;       // [8192] y-pairs (64 KB)
    v2f* zv = yv + 8192;           // [8192] z-pairs (64 KB)
    __shared__ unsigned svals[2][16];  // per-wave max value bits, dbuf
    __shared__ unsigned sidxs[2][16];  // per-wave min candidate idx, dbuf
    v2f pxp[8], ddp[8];
#pragma unroll
    for (int jj = 0; jj < 8; ++jj) {
        int p0 = tid + (jj << 11);          // pair: (p0, p0+1024)
        int p1 = p0 + 1024;
        float x0 = base[p0 * 3 + 0], y0 = base[p0 * 3 + 1], z0 = base[p0 * 3 + 2];
        float x1 = base[p1 * 3 + 0], y1 = base[p1 * 3 + 1], z1 = base[p1 * 3 + 2];
        pxp[jj].x = x0; pxp[jj].y = x1;
        v2f yp; yp.x = y0; yp.y = y1;
        v2f zp; zp.x = z0; zp.y = z1;
        yv[(jj << 10) + tid] = yp;
        zv[(jj << 10) + tid] = zp;
        ddp[jj].x = 1e10f; ddp[jj].y = 1e10f;
    }
    // iteration 0: centroid is point 0
    float cx = base[0], cy = base[1], cz = base[2];
    if (tid == 0) {
        float* o = out + (size_t)b * NS * 3;
        o[0] = cx; o[1] = cy; o[2] = cz;
    }
    __syncthreads();
    for (int i = 1; i < NS; ++i) {
        v2f cx2; cx2.x = cx; cx2.y = cx;
        v2f cy2; cy2.x = cy; cy2.y = cy;
        v2f cz2; cz2.x = cz; cz2.y = cz;
        // value-only scan; 4 independent packed max chains
        v2f cm0, cm1, cm2, cm3;
        cm0.x = -1.f; cm0.y = -1.f; cm1 = cm0; cm2 = cm0; cm3 = cm0;
#pragma unroll
        for (int jj = 0; jj < 8; ++jj) {
            v2f yp = yv[(jj << 10) + tid];
            v2f zp = zv[(jj << 10) + tid];
            // bit-exact: contract(off) -> separate rn mul/add, order ((x2+y2)+z2)
            v2f dx = pxp[jj] - cx2;
            v2f dy = yp - cy2;
            v2f dz = zp - cz2;
            v2f d = (dx * dx + dy * dy) + dz * dz;
            v2f nd;
            nd.x = fminf(ddp[jj].x, d.x);
            nd.y = fminf(ddp[jj].y, d.y);
            ddp[jj] = nd;
            if ((jj & 3) == 0) { cm0.x = fmaxf(cm0.x, nd.x); cm0.y = fmaxf(cm0.y, nd.y); }
            if ((jj & 3) == 1) { cm1.x = fmaxf(cm1.x, nd.x); cm1.y = fmaxf(cm1.y, nd.y); }
            if ((jj & 3) == 2) { cm2.x = fmaxf(cm2.x, nd.x); cm2.y = fmaxf(cm2.y, nd.y); }
            if ((jj & 3) == 3) { cm3.x = fmaxf(cm3.x, nd.x); cm3.y = fmaxf(cm3.y, nd.y); }
        }
        v2f m01; m01.x = fmaxf(cm0.x, cm1.x); m01.y = fmaxf(cm0.y, cm1.y);
        v2f m23; m23.x = fmaxf(cm2.x, cm3.x); m23.y = fmaxf(cm2.y, cm3.y);
        float bv = fmaxf(fmaxf(m01.x, m23.x), fmaxf(m01.y, m23.y));  // thread max (exact)
        // wave(64) value max via DPP on u32 bits (positive floats)
        unsigned vb = (unsigned)__float_as_int(bv);
        UMAX_DPP(vb, 0xB1, 0xf);   // quad_perm xor1
        UMAX_DPP(vb, 0x4E, 0xf);   // quad_perm xor2
        UMAX_DPP(vb, 0x141, 0xf);  // row_half_mirror
        UMAX_DPP(vb, 0x140, 0xf);  // row_mirror
        UMAX_DPP(vb, 0x142, 0xa);  // row_bcast15
        UMAX_DPP(vb, 0x143, 0xc);  // row_bcast31
        if (lane == 63) svals[i & 1][w] = vb;
        __syncthreads();           // barrier 1: wave maxes visible
        // block value max: all lanes reduce the 16 slots
        unsigned wv = svals[i & 1][lane & 15];
        UMAX_DPP(wv, 0xB1, 0xf);
        UMAX_DPP(wv, 0x4E, 0xf);
        UMAX_DPP(wv, 0x141, 0xf);
        UMAX_DPP(wv, 0x140, 0xf);
        float W = __int_as_float((int)wv);  // exact block max, uniform
        // index discovery: only wave(s) holding W scan their registers
        unsigned lidx = 0x7fffffffu;
        if (__any(bv == W)) {
#pragma unroll
            for (int jj = 7; jj >= 0; --jj) {  // descending -> lowest idx wins
                if (ddp[jj].y == W) lidx = (unsigned)(tid + (jj << 11) + 1024);
                if (ddp[jj].x == W) lidx = (unsigned)(tid + (jj << 11));
            }
        }
        UMIN_DPP(lidx, 0xB1, 0xf);
        UMIN_DPP(lidx, 0x4E, 0xf);
        UMIN_DPP(lidx, 0x141, 0xf);
        UMIN_DPP(lidx, 0x140, 0xf);
        UMIN_DPP(lidx, 0x142, 0xa);
        UMIN_DPP(lidx, 0x143, 0xc);
        if (lane == 63) sidxs[i & 1][w] = lidx;
        __syncthreads();           // barrier 2: candidate indices visible
        unsigned ci = sidxs[i & 1][lane & 15];
        UMIN_DPP(ci, 0xB1, 0xf);
        UMIN_DPP(ci, 0x4E, 0xf);
        UMIN_DPP(ci, 0x141, 0xf);
        UMIN_DPP(ci, 0x140, 0xf);
        int ii = __builtin_amdgcn_readfirstlane((int)ci);  // uniform winner
        const float* cp = base + (size_t)ii * 3;
        cx = cp[0]; cy = cp[1]; cz = cp[2];
        if (tid == 0) {
            float* o = out + ((size_t)b * NS + i) * 3;
            o[0] = cx; o[1] = cy; o[2] = cz;
        }
    }
}

// ------------- Ball query (exact expanded-form distance) + gather -------------
__global__ __launch_bounds__(256) void ballq_kernel(const float* __restrict__ xyz,
                                                    const float* __restrict__ pts,
                                                    const float* __restrict__ newxyz,
                                                    float* __restrict__ feat) {
    int w = threadIdx.x >> 6;
    int lane = threadIdx.x & 63;
    int wid = blockIdx.x * 4 + w;   // 0..4095 == b*512+s
    int b = wid >> 9;
    const float* nx = newxyz + (size_t)wid * 3;
    float cx = nx[0], cy = nx[1], cz = nx[2];
    float sa = __fadd_rn(__fadd_rn(__fmul_rn(cx, cx), __fmul_rn(cy, cy)),
                         __fmul_rn(cz, cz));
    __shared__ int sidx[4][64];
    const float* base = xyz + (size_t)b * NPTS * 3;
    int cnt = 0;
    for (int off = 0; off < NPTS && cnt < NK; off += 64) {
        int p = off + lane;
        float bx = base[p * 3 + 0], by = base[p * 3 + 1], bz = base[p * 3 + 2];
        float sb = __fadd_rn(__fadd_rn(__fmul_rn(bx, bx), __fmul_rn(by, by)),
                             __fmul_rn(bz, bz));
        float dt = __fadd_rn(__fadd_rn(__fmul_rn(cx, bx), __fmul_rn(cy, by)),
                             __fmul_rn(cz, bz));
        float sq = __fsub_rn(__fadd_rn(sa, sb), __fmul_rn(2.0f, dt));
        bool inb = !(sq > RAD2);           // strict >, matches reference
        unsigned long long mask = __ballot(inb);
        int pos = cnt + (int)__popcll(mask & ((1ull << lane) - 1ull));
        if (inb && pos < NK) sidx[w][pos] = p;
        cnt += (int)__popcll(mask);
    }
    __syncthreads();
    int filled = cnt < NK ? cnt : NK;
    int sel = (lane < filled) ? lane : 0;
    int p = (filled > 0) ? sidx[w][sel] : 0;  // filled>0 always (self in radius)
    float gx = base[p * 3 + 0], gy = base[p * 3 + 1], gz = base[p * 3 + 2];
    const float* pb = pts + (size_t)b * NPTS * 3;
    float q0 = pb[p * 3 + 0], q1 = pb[p * 3 + 1], q2 = pb[p * 3 + 2];
    float* fr = feat + ((size_t)wid * NK + lane) * 6;
    fr[0] = __fsub_rn(gx, cx);
    fr[1] = __fsub_rn(gy, cy);
    fr[2] = __fsub_rn(gz, cz);
    fr[3] = q0; fr[4] = q1; fr[5] = q2;
}

// ---------------- Layer-0 stats: per-channel sum/sumsq of h0raw ----------------
__global__ __launch_bounds__(256) void stats0_kernel(const float* __restrict__ feat,
                                                     const float* __restrict__ W0,
                                                     const float* __restrict__ b0,
                                                     float* __restrict__ stats) {
    int lane = threadIdx.x & 63;
    int wid = blockIdx.x * 4 + (threadIdx.x >> 6);  // 0..1023
    float w0[6];
#pragma unroll
    for (int j = 0; j < 6; ++j) w0[j] = W0[lane * 6 + j];
    float bb = b0[lane];
    float ssum = 0.f, ssq = 0.f;
    int r0 = wid * 256;
    for (int r = r0; r < r0 + 256; ++r) {
        const float* f = feat + (size_t)r * 6;
        float h = bb;
#pragma unroll
        for (int j = 0; j < 6; ++j) h = fmaf(w0[j], f[j], h);
        ssum += h;
        ssq = fmaf(h, h, ssq);
    }
    atomicAdd(&stats[lane], ssum);
    atomicAdd(&stats[64 + lane], ssq);
}

// helper: split f32 -> (hi, lo) round-to-nearest bf16 pair
__device__ __forceinline__ void bf16_split(float v, unsigned short& hi, unsigned short& lo) {
    unsigned u = __float_as_uint(v);
    unsigned h = (u + 0x7fffu + ((u >> 16) & 1u)) >> 16;
    float rem = v - __uint_as_float(h << 16);
    unsigned ur = __float_as_uint(rem);
    unsigned l = (ur + 0x7fffu + ((ur >> 16) & 1u)) >> 16;
    hi = (unsigned short)h; lo = (unsigned short)l;
}

// ---------------- Layer-1 stats via MFMA bf16-split GEMM ----------------
// Per group (64 rows): h0n (exact; BN0 params derived inline from raw stats0
// sums — deterministic, identical in final_mfma) -> X hi/lo swizzled in LDS;
// H1raw = X*W1^T + b1 via 3-split MFMA; accumulate per-channel sum/sumsq;
// warp shfl-add + LDS block partials -> 2 atomics/channel/block.
__global__ __launch_bounds__(256) void stats1_mfma_kernel(const float* __restrict__ feat,
                                                          const float* __restrict__ W0,
                                                          const float* __restrict__ b0,
                                                          const float* __restrict__ W1,
                                                          const float* __restrict__ b1,
                                                          const float* __restrict__ g0,
                                                          const float* __restrict__ be0,
                                                          float* __restrict__ stats) {
    char* lds = dynsmem;
    int tid = threadIdx.x;
    int lane = tid & 63;
    int w = tid >> 6;
    int g = blockIdx.x * 4 + w;  // 0..4095
    // stage W1 hi/lo swizzled (whole block)
    for (int idx = tid; idx < 8192; idx += 256) {
        int o = idx >> 6, c = idx & 63;
        unsigned short hi, lo;
        bf16_split(W1[idx], hi, lo);
        int byt = (c * 2) ^ ((o & 7) << 4);
        *(unsigned short*)(lds + o * 128 + byt) = hi;
        *(unsigned short*)(lds + 16384 + o * 128 + byt) = lo;
    }
    // BN0 params inline from raw stats0 sums (== old fin0 arithmetic)
    const float inv = 1.0f / (float)MTOT;
    float mu0 = stats[lane] * inv;
    float var0 = fmaxf(stats[64 + lane] * inv - mu0 * mu0, 0.f);
    float a0 = g0[lane] * rsqrtf(var0 + 1e-5f);
    float c0v = fmaf(-mu0, a0, be0[lane]);
    float w0r[6];
#pragma unroll
    for (int j = 0; j < 6; ++j) w0r[j] = W0[lane * 6 + j];
    float b0v = b0[lane];
    char* X = lds + 32768 + w * 16384;  // hi @0, lo @8192
    __syncthreads();  // W1 staged
    const float* fb = feat + (size_t)g * 64 * 6;
#pragma unroll 4
    for (int r = 0; r < 64; ++r) {
        const float* f = fb + r * 6;
        float h = b0v;
#pragma unroll
        for (int j = 0; j < 6; ++j) h = fmaf(w0r[j], f[j], h);
        float hn = fmaxf(fmaf(a0, h, c0v), 0.f);
        unsigned short hi, lo;
        bf16_split(hn, hi, lo);
        int byt = (lane * 2) ^ ((r & 7) << 4);
        *(unsigned short*)(X + r * 128 + byt) = hi;
        *(unsigned short*)(X + 8192 + r * 128 + byt) = lo;
    }
    __syncthreads();  // X + W1 visible
    float b1v[8];
#pragma unroll
    for (int tn = 0; tn < 8; ++tn) b1v[tn] = b1[tn * 16 + (lane & 15)];
    float ssum[8], ssq[8];
#pragma unroll
    for (int tn = 0; tn < 8; ++tn) { ssum[tn] = 0.f; ssq[tn] = 0.f; }
#pragma unroll
    for (int tm = 0; tm < 4; ++tm) {
        bfv8 Ah[2], Al[2];
#pragma unroll
        for (int tk = 0; tk < 2; ++tk) {
            int r = tm * 16 + (lane & 15);
            int colb = (((lane >> 4) * 16) + tk * 64) ^ ((r & 7) << 4);
            Ah[tk] = *(const bfv8*)(X + r * 128 + colb);
            Al[tk] = *(const bfv8*)(X + 8192 + r * 128 + colb);
        }
#pragma unroll
        for (int tn = 0; tn < 8; ++tn) {
            int o = tn * 16 + (lane & 15);
            f32x4 acc = {0.f, 0.f, 0.f, 0.f};
#pragma unroll
            for (int tk = 0; tk < 2; ++tk) {
                int colb = (((lane >> 4) * 16) + tk * 64) ^ ((o & 7) << 4);
                bfv8 Bh = *(const bfv8*)(lds + o * 128 + colb);
                bfv8 Bl = *(const bfv8*)(lds + 16384 + o * 128 + colb);
                acc = __builtin_amdgcn_mfma_f32_16x16x32_bf16(Ah[tk], Bh, acc, 0, 0, 0);
                acc = __builtin_amdgcn_mfma_f32_16x16x32_bf16(Ah[tk], Bl, acc, 0, 0, 0);
                acc = __builtin_amdgcn_mfma_f32_16x16x32_bf16(Al[tk], Bh, acc, 0, 0, 0);
            }
#pragma unroll
            for (int j = 0; j < 4; ++j) {
                float h1 = acc[j] + b1v[tn];
                ssum[tn] += h1;
                ssq[tn] = fmaf(h1, h1, ssq[tn]);
            }
        }
    }
    // reduce across row groups (lanes 16,32 apart)
#pragma unroll
    for (int tn = 0; tn < 8; ++tn) {
        ssum[tn] += __shfl_xor(ssum[tn], 16);
        ssum[tn] += __shfl_xor(ssum[tn], 32);
        ssq[tn] += __shfl_xor(ssq[tn], 16);
        ssq[tn] += __shfl_xor(ssq[tn], 32);
    }
    __syncthreads();  // all GEMM LDS reads done; reuse X region for partials
    float* psum = (float*)(lds + 32768);          // [4][256]
    float* psq  = (float*)(lds + 32768 + 4096);   // [4][256]
    if (lane < 16) {
#pragma unroll
        for (int tn = 0; tn < 8; ++tn) {
            psum[w * 256 + tn * 16 + lane] = ssum[tn];
            psq[w * 256 + tn * 16 + lane] = ssq[tn];
        }
    }
    __syncthreads();
    {
        int ch = tid;  // 256 threads == 256 channels... (C2=128 -> only first 128 valid)
        if (ch < 128) {
            float s = psum[ch] + psum[256 + ch] + psum[512 + ch] + psum[768 + ch];
            float q = psq[ch] + psq[256 + ch] + psq[512 + ch] + psq[768 + ch];
            atomicAdd(&stats[128 + ch], s);
            atomicAdd(&stats[256 + ch], q);
        }
    }
}

// ---------------- Final: MFMA bf16-split GEMM + BN + maxpool ----------------
__global__ __launch_bounds__(256) void final_mfma_kernel(const float* __restrict__ feat,
                                                         const float* __restrict__ W0,
                                                         const float* __restrict__ b0,
                                                         const float* __restrict__ W1,
                                                         const float* __restrict__ b1,
                                                         const float* __restrict__ g0,
                                                         const float* __restrict__ be0,
                                                         const float* __restrict__ g1,
                                                         const float* __restrict__ be1,
                                                         const float* __restrict__ stats,
                                                         float* __restrict__ out) {
    char* lds = dynsmem;
    int tid = threadIdx.x;
    int lane = tid & 63;
    int w = tid >> 6;
    int g = blockIdx.x * 4 + w;  // 0..4095
    for (int idx = tid; idx < 8192; idx += 256) {
        int o = idx >> 6, c = idx & 63;
        unsigned short hi, lo;
        bf16_split(W1[idx], hi, lo);
        int byt = (c * 2) ^ ((o & 7) << 4);
        *(unsigned short*)(lds + o * 128 + byt) = hi;
        *(unsigned short*)(lds + 16384 + o * 128 + byt) = lo;
    }
    // BN0 inline (identical expression to stats1_mfma -> identical h0n)
    const float inv = 1.0f / (float)MTOT;
    float mu0 = stats[lane] * inv;
    float var0 = fmaxf(stats[64 + lane] * inv - mu0 * mu0, 0.f);
    float a0 = g0[lane] * rsqrtf(var0 + 1e-5f);
    float c0v = fmaf(-mu0, a0, be0[lane]);
    float w0r[6];
#pragma unroll
    for (int j = 0; j < 6; ++j) w0r[j] = W0[lane * 6 + j];
    float b0v = b0[lane];
    char* X = lds + 32768 + w * 16384;
    __syncthreads();
    const float* fb = feat + (size_t)g * 64 * 6;
#pragma unroll 4
    for (int r = 0; r < 64; ++r) {
        const float* f = fb + r * 6;
        float h = b0v;
#pragma unroll
        for (int j = 0; j < 6; ++j) h = fmaf(w0r[j], f[j], h);
        float hn = fmaxf(fmaf(a0, h, c0v), 0.f);
        unsigned short hi, lo;
        bf16_split(hn, hi, lo);
        int byt = (lane * 2) ^ ((r & 7) << 4);
        *(unsigned short*)(X + r * 128 + byt) = hi;
        *(unsigned short*)(X + 8192 + r * 128 + byt) = lo;
    }
    __syncthreads();
    // BN1 inline from raw stats1 sums (== old fin1 arithmetic)
    float a1v[8], d1v[8];
#pragma unroll
    for (int tn = 0; tn < 8; ++tn) {
        int o = tn * 16 + (lane & 15);
        float mu1 = stats[128 + o] * inv;
        float var1 = fmaxf(stats[256 + o] * inv - mu1 * mu1, 0.f);
        float a1 = g1[o] * rsqrtf(var1 + 1e-5f);
        float c1 = fmaf(-mu1, a1, be1[o]);
        a1v[tn] = a1;
        d1v[tn] = fmaf(a1, b1[o], c1);  // a1*b1 + c1
    }
    float mx[8];
#pragma unroll
    for (int tn = 0; tn < 8; ++tn) mx[tn] = -1e30f;
#pragma unroll
    for (int tm = 0; tm < 4; ++tm) {
        bfv8 Ah[2], Al[2];
#pragma unroll
        for (int tk = 0; tk < 2; ++tk) {
            int r = tm * 16 + (lane & 15);
            int colb = (((lane >> 4) * 16) + tk * 64) ^ ((r & 7) << 4);
            Ah[tk] = *(const bfv8*)(X + r * 128 + colb);
            Al[tk] = *(const bfv8*)(X + 8192 + r * 128 + colb);
        }
#pragma unroll
        for (int tn = 0; tn < 8; ++tn) {
            int o = tn * 16 + (lane & 15);
            f32x4 acc = {0.f, 0.f, 0.f, 0.f};
#pragma unroll
            for (int tk = 0; tk < 2; ++tk) {
                int colb = (((lane >> 4) * 16) + tk * 64) ^ ((o & 7) << 4);
                bfv8 Bh = *(const bfv8*)(lds + o * 128 + colb);
                bfv8 Bl = *(const bfv8*)(lds + 16384 + o * 128 + colb);
                acc = __builtin_amdgcn_mfma_f32_16x16x32_bf16(Ah[tk], Bh, acc, 0, 0, 0);
                acc = __builtin_amdgcn_mfma_f32_16x16x32_bf16(Ah[tk], Bl, acc, 0, 0, 0);
                acc = __builtin_amdgcn_mfma_f32_16x16x32_bf16(Al[tk], Bh, acc, 0, 0, 0);
            }
            float t0 = fmaxf(fmaf(a1v[tn], acc[0], d1v[tn]), 0.f);
            float t1 = fmaxf(fmaf(a1v[tn], acc[1], d1v[tn]), 0.f);
            float t2 = fmaxf(fmaf(a1v[tn], acc[2], d1v[tn]), 0.f);
            float t3 = fmaxf(fmaf(a1v[tn], acc[3], d1v[tn]), 0.f);
            mx[tn] = fmaxf(mx[tn], fmaxf(fmaxf(t0, t1), fmaxf(t2, t3)));
        }
    }
#pragma unroll
    for (int tn = 0; tn < 8; ++tn) {
        float v = mx[tn];
        v = fmaxf(v, __shfl_xor(v, 16));
        v = fmaxf(v, __shfl_xor(v, 32));
        mx[tn] = v;
    }
    if (lane < 16) {
        size_t ob = 12288 + (size_t)g * 128;
#pragma unroll
        for (int tn = 0; tn < 8; ++tn) out[ob + tn * 16 + lane] = mx[tn];
    }
}

extern "C" void kernel_launch(void* const* d_in, const int* in_sizes, int n_in,
                              void* d_out, int out_size, void* d_ws, size_t ws_size,
                              hipStream_t stream) {
    const float* xyz = (const float*)d_in[0];
    const float* pts = (const float*)d_in[1];
    const float* W0  = (const float*)d_in[2];
    const float* b0  = (const float*)d_in[3];
    const float* g0  = (const float*)d_in[4];
    const float* be0 = (const float*)d_in[5];
    const float* W1  = (const float*)d_in[6];
    const float* b1  = (const float*)d_in[7];
    const float* g1  = (const float*)d_in[8];
    const float* be1 = (const float*)d_in[9];
    float* out = (float*)d_out;

    float* feat  = (float*)d_ws;                     // 262144*6 floats = 6.29 MB
    float* stats = feat + (size_t)MTOT * 6;          // 768 floats

    const int fps_lds = 2 * NPTS * (int)sizeof(float);  // 131072
    (void)hipFuncSetAttribute(reinterpret_cast<const void*>(fps_kernel),
                              hipFuncAttributeMaxDynamicSharedMemorySize, fps_lds);
    const int fm_lds = 98304;  // 32K W1 + 4x16K X
    (void)hipFuncSetAttribute(reinterpret_cast<const void*>(stats1_mfma_kernel),
                              hipFuncAttributeMaxDynamicSharedMemorySize, fm_lds);
    (void)hipFuncSetAttribute(reinterpret_cast<const void*>(final_mfma_kernel),
                              hipFuncAttributeMaxDynamicSharedMemorySize, fm_lds);

    (void)hipMemsetAsync(stats, 0, 384 * sizeof(float), stream);
    fps_kernel<<<NB, 1024, fps_lds, stream>>>(xyz, out);
    ballq_kernel<<<1024, 256, 0, stream>>>(xyz, pts, out, feat);
    stats0_kernel<<<256, 256, 0, stream>>>(feat, W0, b0, stats);
    stats1_mfma_kernel<<<1024, 256, fm_lds, stream>>>(feat, W0, b0, W1, b1, g0, be0, stats);
    final_mfma_kernel<<<1024, 256, fm_lds, stream>>>(feat, W0, b0, W1, b1, g0, be0, g1, be1, stats, out);
}

// Round 14
// 991.508 us; speedup vs baseline: 3.3817x; 1.0728x over previous
//
#include <hip/hip_runtime.h>

#define NB    8
#define NPTS  16384
#define NS    512
#define NK    64
#define C1    64
#define C2    128
#define RAD2  0.25f
#define MTOT  (NB*NS*NK)   // 262144 rows
// ws: feat (6.29MB) | stats (768 f)
// stats: [0:6) m_j=sum f_j | [6:27) M_jk=sum f_j f_k (j<=k, row-major upper)
//        [128:256) s1sum | [256:384) s1sq

typedef float v2f __attribute__((ext_vector_type(2)));
typedef __bf16 bfv8 __attribute__((ext_vector_type(8)));   // MFMA A/B fragment
typedef float f32x4 __attribute__((ext_vector_type(4)));

extern __shared__ char dynsmem[];   // single TU-wide dynamic-LDS symbol

// u32 max/min reduce steps via DPP (positive floats compare as u32).
#define UMAX_DPP(x, CTRL, RM)                                                   \
    do {                                                                        \
        unsigned _m = (unsigned)__builtin_amdgcn_update_dpp((int)(x), (int)(x), \
                                                            CTRL, RM, 0xf, false); \
        x = (x > _m) ? x : _m;                                                  \
    } while (0)
#define UMIN_DPP(x, CTRL, RM)                                                   \
    do {                                                                        \
        unsigned _m = (unsigned)__builtin_amdgcn_update_dpp((int)(x), (int)(x), \
                                                            CTRL, RM, 0xf, false); \
        x = (x < _m) ? x : _m;                                                  \
    } while (0)
// f32 wave-sum step (identity 0 for masked rows); total lands in lane 63.
#define FSUM_DPP(x, CTRL, RM)                                                   \
    do {                                                                        \
        int _b = __builtin_amdgcn_update_dpp(0, __float_as_int(x), CTRL, RM,    \
                                             0xf, false);                       \
        x += __int_as_float(_b);                                                \
    } while (0)

// ---------------- FPS: bit-exact farthest point sampling (r8, 814 us) -------
__global__ __launch_bounds__(1024, 4) void fps_kernel(const float* __restrict__ xyz,
                                                      float* __restrict__ out) {
#pragma clang fp contract(off)
    int b = blockIdx.x;
    int tid = threadIdx.x;
    int lane = tid & 63;
    int w = tid >> 6;  // 16 waves
    const float* base = xyz + (size_t)b * NPTS * 3;
    v2f* yv = (v2f*)dynsmem;       // [8192] y-pairs (64 KB)
    v2f* zv = yv + 8192;           // [8192] z-pairs (64 KB)
    __shared__ unsigned svals[2][16];  // per-wave max value bits, dbuf
    __shared__ unsigned sidxs[2][16];  // per-wave min candidate idx, dbuf
    v2f pxp[8], ddp[8];
#pragma unroll
    for (int jj = 0; jj < 8; ++jj) {
        int p0 = tid + (jj << 11);          // pair: (p0, p0+1024)
        int p1 = p0 + 1024;
        float x0 = base[p0 * 3 + 0], y0 = base[p0 * 3 + 1], z0 = base[p0 * 3 + 2];
        float x1 = base[p1 * 3 + 0], y1 = base[p1 * 3 + 1], z1 = base[p1 * 3 + 2];
        pxp[jj].x = x0; pxp[jj].y = x1;
        v2f yp; yp.x = y0; yp.y = y1;
        v2f zp; zp.x = z0; zp.y = z1;
        yv[(jj << 10) + tid] = yp;
        zv[(jj << 10) + tid] = zp;
        ddp[jj].x = 1e10f; ddp[jj].y = 1e10f;
    }
    // iteration 0: centroid is point 0
    float cx = base[0], cy = base[1], cz = base[2];
    if (tid == 0) {
        float* o = out + (size_t)b * NS * 3;
        o[0] = cx; o[1] = cy; o[2] = cz;
    }
    __syncthreads();
    for (int i = 1; i < NS; ++i) {
        v2f cx2; cx2.x = cx; cx2.y = cx;
        v2f cy2; cy2.x = cy; cy2.y = cy;
        v2f cz2; cz2.x = cz; cz2.y = cz;
        // value-only scan; 4 independent packed max chains
        v2f cm0, cm1, cm2, cm3;
        cm0.x = -1.f; cm0.y = -1.f; cm1 = cm0; cm2 = cm0; cm3 = cm0;
#pragma unroll
        for (int jj = 0; jj < 8; ++jj) {
            v2f yp = yv[(jj << 10) + tid];
            v2f zp = zv[(jj << 10) + tid];
            // bit-exact: contract(off) -> separate rn mul/add, order ((x2+y2)+z2)
            v2f dx = pxp[jj] - cx2;
            v2f dy = yp - cy2;
            v2f dz = zp - cz2;
            v2f d = (dx * dx + dy * dy) + dz * dz;
            v2f nd;
            nd.x = fminf(ddp[jj].x, d.x);
            nd.y = fminf(ddp[jj].y, d.y);
            ddp[jj] = nd;
            if ((jj & 3) == 0) { cm0.x = fmaxf(cm0.x, nd.x); cm0.y = fmaxf(cm0.y, nd.y); }
            if ((jj & 3) == 1) { cm1.x = fmaxf(cm1.x, nd.x); cm1.y = fmaxf(cm1.y, nd.y); }
            if ((jj & 3) == 2) { cm2.x = fmaxf(cm2.x, nd.x); cm2.y = fmaxf(cm2.y, nd.y); }
            if ((jj & 3) == 3) { cm3.x = fmaxf(cm3.x, nd.x); cm3.y = fmaxf(cm3.y, nd.y); }
        }
        v2f m01; m01.x = fmaxf(cm0.x, cm1.x); m01.y = fmaxf(cm0.y, cm1.y);
        v2f m23; m23.x = fmaxf(cm2.x, cm3.x); m23.y = fmaxf(cm2.y, cm3.y);
        float bv = fmaxf(fmaxf(m01.x, m23.x), fmaxf(m01.y, m23.y));  // thread max (exact)
        // wave(64) value max via DPP on u32 bits (positive floats)
        unsigned vb = (unsigned)__float_as_int(bv);
        UMAX_DPP(vb, 0xB1, 0xf);   // quad_perm xor1
        UMAX_DPP(vb, 0x4E, 0xf);   // quad_perm xor2
        UMAX_DPP(vb, 0x141, 0xf);  // row_half_mirror
        UMAX_DPP(vb, 0x140, 0xf);  // row_mirror
        UMAX_DPP(vb, 0x142, 0xa);  // row_bcast15
        UMAX_DPP(vb, 0x143, 0xc);  // row_bcast31
        if (lane == 63) svals[i & 1][w] = vb;
        __syncthreads();           // barrier 1: wave maxes visible
        unsigned wv = svals[i & 1][lane & 15];
        UMAX_DPP(wv, 0xB1, 0xf);
        UMAX_DPP(wv, 0x4E, 0xf);
        UMAX_DPP(wv, 0x141, 0xf);
        UMAX_DPP(wv, 0x140, 0xf);
        float W = __int_as_float((int)wv);  // exact block max, uniform
        // index discovery: only wave(s) holding W scan their registers
        unsigned lidx = 0x7fffffffu;
        if (__any(bv == W)) {
#pragma unroll
            for (int jj = 7; jj >= 0; --jj) {  // descending -> lowest idx wins
                if (ddp[jj].y == W) lidx = (unsigned)(tid + (jj << 11) + 1024);
                if (ddp[jj].x == W) lidx = (unsigned)(tid + (jj << 11));
            }
        }
        UMIN_DPP(lidx, 0xB1, 0xf);
        UMIN_DPP(lidx, 0x4E, 0xf);
        UMIN_DPP(lidx, 0x141, 0xf);
        UMIN_DPP(lidx, 0x140, 0xf);
        UMIN_DPP(lidx, 0x142, 0xa);
        UMIN_DPP(lidx, 0x143, 0xc);
        if (lane == 63) sidxs[i & 1][w] = lidx;
        __syncthreads();           // barrier 2: candidate indices visible
        unsigned ci = sidxs[i & 1][lane & 15];
        UMIN_DPP(ci, 0xB1, 0xf);
        UMIN_DPP(ci, 0x4E, 0xf);
        UMIN_DPP(ci, 0x141, 0xf);
        UMIN_DPP(ci, 0x140, 0xf);
        int ii = __builtin_amdgcn_readfirstlane((int)ci);  // uniform winner
        const float* cp = base + (size_t)ii * 3;
        cx = cp[0]; cy = cp[1]; cz = cp[2];
        if (tid == 0) {
            float* o = out + ((size_t)b * NS + i) * 3;
            o[0] = cx; o[1] = cy; o[2] = cz;
        }
    }
}

// --- Ball query + gather + FUSED layer-0 moment accumulation ---
// Each lane owns one feat row in registers; accumulates the 27 moments
// (m_j, M_jk) via wave DPP-add butterfly -> LDS -> 27 atomics/block.
// BN0 per-channel stats derive exactly from these moments downstream.
__global__ __launch_bounds__(256) void ballq_kernel(const float* __restrict__ xyz,
                                                    const float* __restrict__ pts,
                                                    const float* __restrict__ newxyz,
                                                    float* __restrict__ feat,
                                                    float* __restrict__ stats) {
    int w = threadIdx.x >> 6;
    int lane = threadIdx.x & 63;
    int wid = blockIdx.x * 4 + w;   // 0..4095 == b*512+s
    int b = wid >> 9;
    const float* nx = newxyz + (size_t)wid * 3;
    float cx = nx[0], cy = nx[1], cz = nx[2];
    float sa = __fadd_rn(__fadd_rn(__fmul_rn(cx, cx), __fmul_rn(cy, cy)),
                         __fmul_rn(cz, cz));
    __shared__ int sidx[4][64];
    __shared__ float pm[4][27];
    const float* base = xyz + (size_t)b * NPTS * 3;
    int cnt = 0;
    for (int off = 0; off < NPTS && cnt < NK; off += 64) {
        int p = off + lane;
        float bx = base[p * 3 + 0], by = base[p * 3 + 1], bz = base[p * 3 + 2];
        float sb = __fadd_rn(__fadd_rn(__fmul_rn(bx, bx), __fmul_rn(by, by)),
                             __fmul_rn(bz, bz));
        float dt = __fadd_rn(__fadd_rn(__fmul_rn(cx, bx), __fmul_rn(cy, by)),
                             __fmul_rn(cz, bz));
        float sq = __fsub_rn(__fadd_rn(sa, sb), __fmul_rn(2.0f, dt));
        bool inb = !(sq > RAD2);           // strict >, matches reference
        unsigned long long mask = __ballot(inb);
        int pos = cnt + (int)__popcll(mask & ((1ull << lane) - 1ull));
        if (inb && pos < NK) sidx[w][pos] = p;
        cnt += (int)__popcll(mask);
    }
    __syncthreads();
    int filled = cnt < NK ? cnt : NK;
    int sel = (lane < filled) ? lane : 0;
    int p = (filled > 0) ? sidx[w][sel] : 0;  // filled>0 always (self in radius)
    float gx = base[p * 3 + 0], gy = base[p * 3 + 1], gz = base[p * 3 + 2];
    const float* pb = pts + (size_t)b * NPTS * 3;
    float rowf[6];
    rowf[0] = __fsub_rn(gx, cx);
    rowf[1] = __fsub_rn(gy, cy);
    rowf[2] = __fsub_rn(gz, cz);
    rowf[3] = pb[p * 3 + 0];
    rowf[4] = pb[p * 3 + 1];
    rowf[5] = pb[p * 3 + 2];
    float* fr = feat + ((size_t)wid * NK + lane) * 6;
#pragma unroll
    for (int j = 0; j < 6; ++j) fr[j] = rowf[j];
    // 27 moments of this lane's row
    float mom[27];
#pragma unroll
    for (int j = 0; j < 6; ++j) mom[j] = rowf[j];
    {
        int t = 6;
#pragma unroll
        for (int j = 0; j < 6; ++j)
#pragma unroll
            for (int k = j; k < 6; ++k) mom[t++] = rowf[j] * rowf[k];
    }
#pragma unroll
    for (int t = 0; t < 27; ++t) {
        FSUM_DPP(mom[t], 0xB1, 0xf);
        FSUM_DPP(mom[t], 0x4E, 0xf);
        FSUM_DPP(mom[t], 0x141, 0xf);
        FSUM_DPP(mom[t], 0x140, 0xf);
        FSUM_DPP(mom[t], 0x142, 0xa);
        FSUM_DPP(mom[t], 0x143, 0xc);
        if (lane == 63) pm[w][t] = mom[t];  // wave total in lane 63
    }
    __syncthreads();
    if (threadIdx.x < 27) {
        int t = threadIdx.x;
        float s = pm[0][t] + pm[1][t] + pm[2][t] + pm[3][t];
        atomicAdd(&stats[t], s);
    }
}

// helper: split f32 -> (hi, lo) round-to-nearest bf16 pair
__device__ __forceinline__ void bf16_split(float v, unsigned short& hi, unsigned short& lo) {
    unsigned u = __float_as_uint(v);
    unsigned h = (u + 0x7fffu + ((u >> 16) & 1u)) >> 16;
    float rem = v - __uint_as_float(h << 16);
    unsigned ur = __float_as_uint(rem);
    unsigned l = (ur + 0x7fffu + ((ur >> 16) & 1u)) >> 16;
    hi = (unsigned short)h; lo = (unsigned short)l;
}

// BN0 params for channel c (= lane) from the 27 global moments.
// Identical expression in stats1_mfma and final_mfma -> identical h0n.
__device__ __forceinline__ void bn0_from_moments(const float* __restrict__ stats,
                                                 const float* __restrict__ g0,
                                                 const float* __restrict__ be0,
                                                 const float* w0r, float b0v,
                                                 int lane, float& a0, float& c0v) {
    const float inv = 1.0f / (float)MTOT;
    float m6[6];
#pragma unroll
    for (int j = 0; j < 6; ++j) m6[j] = stats[j];
    float s = 0.f;
#pragma unroll
    for (int j = 0; j < 6; ++j) s = fmaf(w0r[j], m6[j], s);
    float quad = 0.f;
    {
        int t = 6;
#pragma unroll
        for (int j = 0; j < 6; ++j)
#pragma unroll
            for (int k = j; k < 6; ++k) {
                float coef = w0r[j] * w0r[k];
                if (j != k) coef = coef + coef;
                quad = fmaf(coef, stats[t], quad);
                ++t;
            }
    }
    float mu0 = fmaf(s, inv, b0v);
    float e2 = fmaf(quad, inv, fmaf(2.f * b0v * s, inv, b0v * b0v));
    float var0 = fmaxf(e2 - mu0 * mu0, 0.f);
    a0 = g0[lane] * rsqrtf(var0 + 1e-5f);
    c0v = fmaf(-mu0, a0, be0[lane]);
}

// ---------------- Layer-1 stats via MFMA bf16-split GEMM ----------------
__global__ __launch_bounds__(256) void stats1_mfma_kernel(const float* __restrict__ feat,
                                                          const float* __restrict__ W0,
                                                          const float* __restrict__ b0,
                                                          const float* __restrict__ W1,
                                                          const float* __restrict__ b1,
                                                          const float* __restrict__ g0,
                                                          const float* __restrict__ be0,
                                                          float* __restrict__ stats) {
    char* lds = dynsmem;
    int tid = threadIdx.x;
    int lane = tid & 63;
    int w = tid >> 6;
    int g = blockIdx.x * 4 + w;  // 0..4095
    for (int idx = tid; idx < 8192; idx += 256) {
        int o = idx >> 6, c = idx & 63;
        unsigned short hi, lo;
        bf16_split(W1[idx], hi, lo);
        int byt = (c * 2) ^ ((o & 7) << 4);
        *(unsigned short*)(lds + o * 128 + byt) = hi;
        *(unsigned short*)(lds + 16384 + o * 128 + byt) = lo;
    }
    float w0r[6];
#pragma unroll
    for (int j = 0; j < 6; ++j) w0r[j] = W0[lane * 6 + j];
    float b0v = b0[lane];
    float a0, c0v;
    bn0_from_moments(stats, g0, be0, w0r, b0v, lane, a0, c0v);
    char* X = lds + 32768 + w * 16384;  // hi @0, lo @8192
    __syncthreads();  // W1 staged
    const float* fb = feat + (size_t)g * 64 * 6;
#pragma unroll 4
    for (int r = 0; r < 64; ++r) {
        const float* f = fb + r * 6;
        float h = b0v;
#pragma unroll
        for (int j = 0; j < 6; ++j) h = fmaf(w0r[j], f[j], h);
        float hn = fmaxf(fmaf(a0, h, c0v), 0.f);
        unsigned short hi, lo;
        bf16_split(hn, hi, lo);
        int byt = (lane * 2) ^ ((r & 7) << 4);
        *(unsigned short*)(X + r * 128 + byt) = hi;
        *(unsigned short*)(X + 8192 + r * 128 + byt) = lo;
    }
    __syncthreads();  // X + W1 visible
    float b1v[8];
#pragma unroll
    for (int tn = 0; tn < 8; ++tn) b1v[tn] = b1[tn * 16 + (lane & 15)];
    float ssum[8], ssq[8];
#pragma unroll
    for (int tn = 0; tn < 8; ++tn) { ssum[tn] = 0.f; ssq[tn] = 0.f; }
#pragma unroll
    for (int tm = 0; tm < 4; ++tm) {
        bfv8 Ah[2], Al[2];
#pragma unroll
        for (int tk = 0; tk < 2; ++tk) {
            int r = tm * 16 + (lane & 15);
            int colb = (((lane >> 4) * 16) + tk * 64) ^ ((r & 7) << 4);
            Ah[tk] = *(const bfv8*)(X + r * 128 + colb);
            Al[tk] = *(const bfv8*)(X + 8192 + r * 128 + colb);
        }
#pragma unroll
        for (int tn = 0; tn < 8; ++tn) {
            int o = tn * 16 + (lane & 15);
            f32x4 acc = {0.f, 0.f, 0.f, 0.f};
#pragma unroll
            for (int tk = 0; tk < 2; ++tk) {
                int colb = (((lane >> 4) * 16) + tk * 64) ^ ((o & 7) << 4);
                bfv8 Bh = *(const bfv8*)(lds + o * 128 + colb);
                bfv8 Bl = *(const bfv8*)(lds + 16384 + o * 128 + colb);
                acc = __builtin_amdgcn_mfma_f32_16x16x32_bf16(Ah[tk], Bh, acc, 0, 0, 0);
                acc = __builtin_amdgcn_mfma_f32_16x16x32_bf16(Ah[tk], Bl, acc, 0, 0, 0);
                acc = __builtin_amdgcn_mfma_f32_16x16x32_bf16(Al[tk], Bh, acc, 0, 0, 0);
            }
#pragma unroll
            for (int j = 0; j < 4; ++j) {
                float h1 = acc[j] + b1v[tn];
                ssum[tn] += h1;
                ssq[tn] = fmaf(h1, h1, ssq[tn]);
            }
        }
    }
#pragma unroll
    for (int tn = 0; tn < 8; ++tn) {
        ssum[tn] += __shfl_xor(ssum[tn], 16);
        ssum[tn] += __shfl_xor(ssum[tn], 32);
        ssq[tn] += __shfl_xor(ssq[tn], 16);
        ssq[tn] += __shfl_xor(ssq[tn], 32);
    }
    __syncthreads();  // all GEMM LDS reads done; reuse X region for partials
    float* psum = (float*)(lds + 32768);          // [4][256]
    float* psq  = (float*)(lds + 32768 + 4096);   // [4][256]
    if (lane < 16) {
#pragma unroll
        for (int tn = 0; tn < 8; ++tn) {
            psum[w * 256 + tn * 16 + lane] = ssum[tn];
            psq[w * 256 + tn * 16 + lane] = ssq[tn];
        }
    }
    __syncthreads();
    if (tid < 128) {
        int ch = tid;
        float s = psum[ch] + psum[256 + ch] + psum[512 + ch] + psum[768 + ch];
        float q = psq[ch] + psq[256 + ch] + psq[512 + ch] + psq[768 + ch];
        atomicAdd(&stats[128 + ch], s);
        atomicAdd(&stats[256 + ch], q);
    }
}

// ---------------- Final: MFMA bf16-split GEMM + BN + maxpool ----------------
__global__ __launch_bounds__(256) void final_mfma_kernel(const float* __restrict__ feat,
                                                         const float* __restrict__ W0,
                                                         const float* __restrict__ b0,
                                                         const float* __restrict__ W1,
                                                         const float* __restrict__ b1,
                                                         const float* __restrict__ g0,
                                                         const float* __restrict__ be0,
                                                         const float* __restrict__ g1,
                                                         const float* __restrict__ be1,
                                                         const float* __restrict__ stats,
                                                         float* __restrict__ out) {
    char* lds = dynsmem;
    int tid = threadIdx.x;
    int lane = tid & 63;
    int w = tid >> 6;
    int g = blockIdx.x * 4 + w;  // 0..4095
    for (int idx = tid; idx < 8192; idx += 256) {
        int o = idx >> 6, c = idx & 63;
        unsigned short hi, lo;
        bf16_split(W1[idx], hi, lo);
        int byt = (c * 2) ^ ((o & 7) << 4);
        *(unsigned short*)(lds + o * 128 + byt) = hi;
        *(unsigned short*)(lds + 16384 + o * 128 + byt) = lo;
    }
    float w0r[6];
#pragma unroll
    for (int j = 0; j < 6; ++j) w0r[j] = W0[lane * 6 + j];
    float b0v = b0[lane];
    float a0, c0v;
    bn0_from_moments(stats, g0, be0, w0r, b0v, lane, a0, c0v);
    char* X = lds + 32768 + w * 16384;
    __syncthreads();
    const float* fb = feat + (size_t)g * 64 * 6;
#pragma unroll 4
    for (int r = 0; r < 64; ++r) {
        const float* f = fb + r * 6;
        float h = b0v;
#pragma unroll
        for (int j = 0; j < 6; ++j) h = fmaf(w0r[j], f[j], h);
        float hn = fmaxf(fmaf(a0, h, c0v), 0.f);
        unsigned short hi, lo;
        bf16_split(hn, hi, lo);
        int byt = (lane * 2) ^ ((r & 7) << 4);
        *(unsigned short*)(X + r * 128 + byt) = hi;
        *(unsigned short*)(X + 8192 + r * 128 + byt) = lo;
    }
    __syncthreads();
    // BN1 inline from raw stats1 sums
    const float inv = 1.0f / (float)MTOT;
    float a1v[8], d1v[8];
#pragma unroll
    for (int tn = 0; tn < 8; ++tn) {
        int o = tn * 16 + (lane & 15);
        float mu1 = stats[128 + o] * inv;
        float var1 = fmaxf(stats[256 + o] * inv - mu1 * mu1, 0.f);
        float a1 = g1[o] * rsqrtf(var1 + 1e-5f);
        float c1 = fmaf(-mu1, a1, be1[o]);
        a1v[tn] = a1;
        d1v[tn] = fmaf(a1, b1[o], c1);  // a1*b1 + c1
    }
    float mx[8];
#pragma unroll
    for (int tn = 0; tn < 8; ++tn) mx[tn] = -1e30f;
#pragma unroll
    for (int tm = 0; tm < 4; ++tm) {
        bfv8 Ah[2], Al[2];
#pragma unroll
        for (int tk = 0; tk < 2; ++tk) {
            int r = tm * 16 + (lane & 15);
            int colb = (((lane >> 4) * 16) + tk * 64) ^ ((r & 7) << 4);
            Ah[tk] = *(const bfv8*)(X + r * 128 + colb);
            Al[tk] = *(const bfv8*)(X + 8192 + r * 128 + colb);
        }
#pragma unroll
        for (int tn = 0; tn < 8; ++tn) {
            int o = tn * 16 + (lane & 15);
            f32x4 acc = {0.f, 0.f, 0.f, 0.f};
#pragma unroll
            for (int tk = 0; tk < 2; ++tk) {
                int colb = (((lane >> 4) * 16) + tk * 64) ^ ((o & 7) << 4);
                bfv8 Bh = *(const bfv8*)(lds + o * 128 + colb);
                bfv8 Bl = *(const bfv8*)(lds + 16384 + o * 128 + colb);
                acc = __builtin_amdgcn_mfma_f32_16x16x32_bf16(Ah[tk], Bh, acc, 0, 0, 0);
                acc = __builtin_amdgcn_mfma_f32_16x16x32_bf16(Ah[tk], Bl, acc, 0, 0, 0);
                acc = __builtin_amdgcn_mfma_f32_16x16x32_bf16(Al[tk], Bh, acc, 0, 0, 0);
            }
            float t0 = fmaxf(fmaf(a1v[tn], acc[0], d1v[tn]), 0.f);
            float t1 = fmaxf(fmaf(a1v[tn], acc[1], d1v[tn]), 0.f);
            float t2 = fmaxf(fmaf(a1v[tn], acc[2], d1v[tn]), 0.f);
            float t3 = fmaxf(fmaf(a1v[tn], acc[3], d1v[tn]), 0.f);
            mx[tn] = fmaxf(mx[tn], fmaxf(fmaxf(t0, t1), fmaxf(t2, t3)));
        }
    }
#pragma unroll
    for (int tn = 0; tn < 8; ++tn) {
        float v = mx[tn];
        v = fmaxf(v, __shfl_xor(v, 16));
        v = fmaxf(v, __shfl_xor(v, 32));
        mx[tn] = v;
    }
    if (lane < 16) {
        size_t ob = 12288 + (size_t)g * 128;
#pragma unroll
        for (int tn = 0; tn < 8; ++tn) out[ob + tn * 16 + lane] = mx[tn];
    }
}

extern "C" void kernel_launch(void* const* d_in, const int* in_sizes, int n_in,
                              void* d_out, int out_size, void* d_ws, size_t ws_size,
                              hipStream_t stream) {
    const float* xyz = (const float*)d_in[0];
    const float* pts = (const float*)d_in[1];
    const float* W0  = (const float*)d_in[2];
    const float* b0  = (const float*)d_in[3];
    const float* g0  = (const float*)d_in[4];
    const float* be0 = (const float*)d_in[5];
    const float* W1  = (const float*)d_in[6];
    const float* b1  = (const float*)d_in[7];
    const float* g1  = (const float*)d_in[8];
    const float* be1 = (const float*)d_in[9];
    float* out = (float*)d_out;

    float* feat  = (float*)d_ws;                     // 262144*6 floats = 6.29 MB
    float* stats = feat + (size_t)MTOT * 6;          // 768 floats

    const int fps_lds = 2 * NPTS * (int)sizeof(float);  // 131072
    (void)hipFuncSetAttribute(reinterpret_cast<const void*>(fps_kernel),
                              hipFuncAttributeMaxDynamicSharedMemorySize, fps_lds);
    const int fm_lds = 98304;  // 32K W1 + 4x16K X
    (void)hipFuncSetAttribute(reinterpret_cast<const void*>(stats1_mfma_kernel),
                              hipFuncAttributeMaxDynamicSharedMemorySize, fm_lds);
    (void)hipFuncSetAttribute(reinterpret_cast<const void*>(final_mfma_kernel),
                              hipFuncAttributeMaxDynamicSharedMemorySize, fm_lds);

    (void)hipMemsetAsync(stats, 0, 384 * sizeof(float), stream);
    fps_kernel<<<NB, 1024, fps_lds, stream>>>(xyz, out);
    ballq_kernel<<<1024, 256, 0, stream>>>(xyz, pts, out, feat, stats);
    stats1_mfma_kernel<<<1024, 256, fm_lds, stream>>>(feat, W0, b0, W1, b1, g0, be0, stats);
    final_mfma_kernel<<<1024, 256, fm_lds, stream>>>(feat, W0, b0, W1, b1, g0, be0, g1, be1, stats, out);
}

// Round 15
// 944.163 us; speedup vs baseline: 3.5512x; 1.0501x over previous
//
#include <hip/hip_runtime.h>

#define NB    8
#define NPTS  16384
#define NS    512
#define NK    64
#define C1    64
#define C2    128
#define RAD2  0.25f
#define MTOT  (NB*NS*NK)   // 262144 rows
// ws: feat (6.29MB) | stats (768 f)
// stats: [0:6) m_j=sum f_j | [6:27) M_jk=sum f_j f_k (j<=k, row-major upper)
//        [128:256) s1sum | [256:384) s1sq

typedef float v2f __attribute__((ext_vector_type(2)));
typedef __bf16 bfv8 __attribute__((ext_vector_type(8)));   // MFMA A/B fragment
typedef float f32x4 __attribute__((ext_vector_type(4)));

extern __shared__ char dynsmem[];   // single TU-wide dynamic-LDS symbol

// Forbid AGPR allocation if the compiler supports it (gfx950 unified RF:
// the allocator otherwise parks cold arrays in AGPRs -> ~96 accvgpr
// moves/iter in the fps scan). Guarded: zero compile risk.
#if defined(__has_attribute)
#if __has_attribute(amdgpu_agpr_alloc)
#define NO_AGPR __attribute__((amdgpu_agpr_alloc(0)))
#else
#define NO_AGPR
#endif
#else
#define NO_AGPR
#endif

// u32 max/min reduce steps via DPP (positive floats compare as u32).
#define UMAX_DPP(x, CTRL, RM)                                                   \
    do {                                                                        \
        unsigned _m = (unsigned)__builtin_amdgcn_update_dpp((int)(x), (int)(x), \
                                                            CTRL, RM, 0xf, false); \
        x = (x > _m) ? x : _m;                                                  \
    } while (0)
#define UMIN_DPP(x, CTRL, RM)                                                   \
    do {                                                                        \
        unsigned _m = (unsigned)__builtin_amdgcn_update_dpp((int)(x), (int)(x), \
                                                            CTRL, RM, 0xf, false); \
        x = (x < _m) ? x : _m;                                                  \
    } while (0)
// f32 wave-sum step (identity 0 for masked rows); total lands in lane 63.
#define FSUM_DPP(x, CTRL, RM)                                                   \
    do {                                                                        \
        int _b = __builtin_amdgcn_update_dpp(0, __float_as_int(x), CTRL, RM,    \
                                             0xf, false);                       \
        x += __int_as_float(_b);                                                \
    } while (0)

// ---------------- FPS: bit-exact farthest point sampling ----------------
// r8 structure + this round: NO_AGPR, yz packed float4 (1 b128/pair),
// candidate-only index UMIN, stats zeroing folded in (block 0).
__global__ __launch_bounds__(1024, 4) NO_AGPR
void fps_kernel(const float* __restrict__ xyz, float* __restrict__ out,
                float* __restrict__ stats) {
#pragma clang fp contract(off)
    int b = blockIdx.x;
    int tid = threadIdx.x;
    int lane = tid & 63;
    int w = tid >> 6;  // 16 waves
    if (b == 0 && tid < 384) stats[tid] = 0.f;  // replaces hipMemsetAsync
    const float* base = xyz + (size_t)b * NPTS * 3;
    float4* yzv = (float4*)dynsmem;    // [8192] = 128 KB: [y0,y1,z0,z1] per pair
    __shared__ unsigned svals[2][16];  // per-wave max value bits, dbuf
    __shared__ unsigned sidxs[2][16];  // per-wave min candidate idx, dbuf
    v2f pxp[8], ddp[8];
#pragma unroll
    for (int jj = 0; jj < 8; ++jj) {
        int p0 = tid + (jj << 11);          // pair: (p0, p0+1024)
        int p1 = p0 + 1024;
        float x0 = base[p0 * 3 + 0], y0 = base[p0 * 3 + 1], z0 = base[p0 * 3 + 2];
        float x1 = base[p1 * 3 + 0], y1 = base[p1 * 3 + 1], z1 = base[p1 * 3 + 2];
        pxp[jj].x = x0; pxp[jj].y = x1;
        float4 q; q.x = y0; q.y = y1; q.z = z0; q.w = z1;
        yzv[(jj << 10) + tid] = q;
        ddp[jj].x = 1e10f; ddp[jj].y = 1e10f;
    }
    // iteration 0: centroid is point 0
    float cx = base[0], cy = base[1], cz = base[2];
    if (tid == 0) {
        float* o = out + (size_t)b * NS * 3;
        o[0] = cx; o[1] = cy; o[2] = cz;
    }
    __syncthreads();
    for (int i = 1; i < NS; ++i) {
        v2f cx2; cx2.x = cx; cx2.y = cx;
        v2f cy2; cy2.x = cy; cy2.y = cy;
        v2f cz2; cz2.x = cz; cz2.y = cz;
        // value-only scan; 4 independent packed max chains
        v2f cm0, cm1, cm2, cm3;
        cm0.x = -1.f; cm0.y = -1.f; cm1 = cm0; cm2 = cm0; cm3 = cm0;
#pragma unroll
        for (int jj = 0; jj < 8; ++jj) {
            float4 q = yzv[(jj << 10) + tid];
            v2f yp; yp.x = q.x; yp.y = q.y;
            v2f zp; zp.x = q.z; zp.y = q.w;
            // bit-exact: contract(off) -> separate rn mul/add, order ((x2+y2)+z2)
            v2f dx = pxp[jj] - cx2;
            v2f dy = yp - cy2;
            v2f dz = zp - cz2;
            v2f d = (dx * dx + dy * dy) + dz * dz;
            v2f nd;
            nd.x = fminf(ddp[jj].x, d.x);
            nd.y = fminf(ddp[jj].y, d.y);
            ddp[jj] = nd;
            if ((jj & 3) == 0) { cm0.x = fmaxf(cm0.x, nd.x); cm0.y = fmaxf(cm0.y, nd.y); }
            if ((jj & 3) == 1) { cm1.x = fmaxf(cm1.x, nd.x); cm1.y = fmaxf(cm1.y, nd.y); }
            if ((jj & 3) == 2) { cm2.x = fmaxf(cm2.x, nd.x); cm2.y = fmaxf(cm2.y, nd.y); }
            if ((jj & 3) == 3) { cm3.x = fmaxf(cm3.x, nd.x); cm3.y = fmaxf(cm3.y, nd.y); }
        }
        v2f m01; m01.x = fmaxf(cm0.x, cm1.x); m01.y = fmaxf(cm0.y, cm1.y);
        v2f m23; m23.x = fmaxf(cm2.x, cm3.x); m23.y = fmaxf(cm2.y, cm3.y);
        float bv = fmaxf(fmaxf(m01.x, m23.x), fmaxf(m01.y, m23.y));  // thread max (exact)
        // wave(64) value max via DPP on u32 bits (positive floats)
        unsigned vb = (unsigned)__float_as_int(bv);
        UMAX_DPP(vb, 0xB1, 0xf);   // quad_perm xor1
        UMAX_DPP(vb, 0x4E, 0xf);   // quad_perm xor2
        UMAX_DPP(vb, 0x141, 0xf);  // row_half_mirror
        UMAX_DPP(vb, 0x140, 0xf);  // row_mirror
        UMAX_DPP(vb, 0x142, 0xa);  // row_bcast15
        UMAX_DPP(vb, 0x143, 0xc);  // row_bcast31
        if (lane == 63) svals[i & 1][w] = vb;
        __syncthreads();           // barrier 1: wave maxes visible
        unsigned wv = svals[i & 1][lane & 15];
        UMAX_DPP(wv, 0xB1, 0xf);
        UMAX_DPP(wv, 0x4E, 0xf);
        UMAX_DPP(wv, 0x141, 0xf);
        UMAX_DPP(wv, 0x140, 0xf);
        float W = __int_as_float((int)wv);  // exact block max, uniform
        // index discovery + UMIN chain: only candidate wave(s) pay for it
        unsigned lidx = 0x7fffffffu;
        if (__any(bv == W)) {
#pragma unroll
            for (int jj = 7; jj >= 0; --jj) {  // descending -> lowest idx wins
                if (ddp[jj].y == W) lidx = (unsigned)(tid + (jj << 11) + 1024);
                if (ddp[jj].x == W) lidx = (unsigned)(tid + (jj << 11));
            }
            UMIN_DPP(lidx, 0xB1, 0xf);
            UMIN_DPP(lidx, 0x4E, 0xf);
            UMIN_DPP(lidx, 0x141, 0xf);
            UMIN_DPP(lidx, 0x140, 0xf);
            UMIN_DPP(lidx, 0x142, 0xa);
            UMIN_DPP(lidx, 0x143, 0xc);
        }
        if (lane == 63) sidxs[i & 1][w] = lidx;  // non-candidates: identity
        __syncthreads();           // barrier 2: candidate indices visible
        unsigned ci = sidxs[i & 1][lane & 15];
        UMIN_DPP(ci, 0xB1, 0xf);
        UMIN_DPP(ci, 0x4E, 0xf);
        UMIN_DPP(ci, 0x141, 0xf);
        UMIN_DPP(ci, 0x140, 0xf);
        int ii = __builtin_amdgcn_readfirstlane((int)ci);  // uniform winner
        const float* cp = base + (size_t)ii * 3;
        cx = cp[0]; cy = cp[1]; cz = cp[2];
        if (tid == 0) {
            float* o = out + ((size_t)b * NS + i) * 3;
            o[0] = cx; o[1] = cy; o[2] = cz;
        }
    }
}

// --- Ball query + gather + FUSED layer-0 moment accumulation ---
__global__ __launch_bounds__(256) void ballq_kernel(const float* __restrict__ xyz,
                                                    const float* __restrict__ pts,
                                                    const float* __restrict__ newxyz,
                                                    float* __restrict__ feat,
                                                    float* __restrict__ stats) {
    int w = threadIdx.x >> 6;
    int lane = threadIdx.x & 63;
    int wid = blockIdx.x * 4 + w;   // 0..4095 == b*512+s
    int b = wid >> 9;
    const float* nx = newxyz + (size_t)wid * 3;
    float cx = nx[0], cy = nx[1], cz = nx[2];
    float sa = __fadd_rn(__fadd_rn(__fmul_rn(cx, cx), __fmul_rn(cy, cy)),
                         __fmul_rn(cz, cz));
    __shared__ int sidx[4][64];
    __shared__ float pm[4][27];
    const float* base = xyz + (size_t)b * NPTS * 3;
    int cnt = 0;
    for (int off = 0; off < NPTS && cnt < NK; off += 64) {
        int p = off + lane;
        float bx = base[p * 3 + 0], by = base[p * 3 + 1], bz = base[p * 3 + 2];
        float sb = __fadd_rn(__fadd_rn(__fmul_rn(bx, bx), __fmul_rn(by, by)),
                             __fmul_rn(bz, bz));
        float dt = __fadd_rn(__fadd_rn(__fmul_rn(cx, bx), __fmul_rn(cy, by)),
                             __fmul_rn(cz, bz));
        float sq = __fsub_rn(__fadd_rn(sa, sb), __fmul_rn(2.0f, dt));
        bool inb = !(sq > RAD2);           // strict >, matches reference
        unsigned long long mask = __ballot(inb);
        int pos = cnt + (int)__popcll(mask & ((1ull << lane) - 1ull));
        if (inb && pos < NK) sidx[w][pos] = p;
        cnt += (int)__popcll(mask);
    }
    __syncthreads();
    int filled = cnt < NK ? cnt : NK;
    int sel = (lane < filled) ? lane : 0;
    int p = (filled > 0) ? sidx[w][sel] : 0;  // filled>0 always (self in radius)
    float gx = base[p * 3 + 0], gy = base[p * 3 + 1], gz = base[p * 3 + 2];
    const float* pb = pts + (size_t)b * NPTS * 3;
    float rowf[6];
    rowf[0] = __fsub_rn(gx, cx);
    rowf[1] = __fsub_rn(gy, cy);
    rowf[2] = __fsub_rn(gz, cz);
    rowf[3] = pb[p * 3 + 0];
    rowf[4] = pb[p * 3 + 1];
    rowf[5] = pb[p * 3 + 2];
    float* fr = feat + ((size_t)wid * NK + lane) * 6;
#pragma unroll
    for (int j = 0; j < 6; ++j) fr[j] = rowf[j];
    // 27 moments of this lane's row
    float mom[27];
#pragma unroll
    for (int j = 0; j < 6; ++j) mom[j] = rowf[j];
    {
        int t = 6;
#pragma unroll
        for (int j = 0; j < 6; ++j)
#pragma unroll
            for (int k = j; k < 6; ++k) mom[t++] = rowf[j] * rowf[k];
    }
#pragma unroll
    for (int t = 0; t < 27; ++t) {
        FSUM_DPP(mom[t], 0xB1, 0xf);
        FSUM_DPP(mom[t], 0x4E, 0xf);
        FSUM_DPP(mom[t], 0x141, 0xf);
        FSUM_DPP(mom[t], 0x140, 0xf);
        FSUM_DPP(mom[t], 0x142, 0xa);
        FSUM_DPP(mom[t], 0x143, 0xc);
        if (lane == 63) pm[w][t] = mom[t];  // wave total in lane 63
    }
    __syncthreads();
    if (threadIdx.x < 27) {
        int t = threadIdx.x;
        float s = pm[0][t] + pm[1][t] + pm[2][t] + pm[3][t];
        atomicAdd(&stats[t], s);
    }
}

// helper: split f32 -> (hi, lo) round-to-nearest bf16 pair
__device__ __forceinline__ void bf16_split(float v, unsigned short& hi, unsigned short& lo) {
    unsigned u = __float_as_uint(v);
    unsigned h = (u + 0x7fffu + ((u >> 16) & 1u)) >> 16;
    float rem = v - __uint_as_float(h << 16);
    unsigned ur = __float_as_uint(rem);
    unsigned l = (ur + 0x7fffu + ((ur >> 16) & 1u)) >> 16;
    hi = (unsigned short)h; lo = (unsigned short)l;
}

// BN0 params for channel c (= lane) from the 27 global moments.
// Identical expression in stats1_mfma and final_mfma -> identical h0n.
__device__ __forceinline__ void bn0_from_moments(const float* __restrict__ stats,
                                                 const float* __restrict__ g0,
                                                 const float* __restrict__ be0,
                                                 const float* w0r, float b0v,
                                                 int lane, float& a0, float& c0v) {
    const float inv = 1.0f / (float)MTOT;
    float m6[6];
#pragma unroll
    for (int j = 0; j < 6; ++j) m6[j] = stats[j];
    float s = 0.f;
#pragma unroll
    for (int j = 0; j < 6; ++j) s = fmaf(w0r[j], m6[j], s);
    float quad = 0.f;
    {
        int t = 6;
#pragma unroll
        for (int j = 0; j < 6; ++j)
#pragma unroll
            for (int k = j; k < 6; ++k) {
                float coef = w0r[j] * w0r[k];
                if (j != k) coef = coef + coef;
                quad = fmaf(coef, stats[t], quad);
                ++t;
            }
    }
    float mu0 = fmaf(s, inv, b0v);
    float e2 = fmaf(quad, inv, fmaf(2.f * b0v * s, inv, b0v * b0v));
    float var0 = fmaxf(e2 - mu0 * mu0, 0.f);
    a0 = g0[lane] * rsqrtf(var0 + 1e-5f);
    c0v = fmaf(-mu0, a0, be0[lane]);
}

// ---------------- Layer-1 stats via MFMA bf16-split GEMM ----------------
__global__ __launch_bounds__(256) void stats1_mfma_kernel(const float* __restrict__ feat,
                                                          const float* __restrict__ W0,
                                                          const float* __restrict__ b0,
                                                          const float* __restrict__ W1,
                                                          const float* __restrict__ b1,
                                                          const float* __restrict__ g0,
                                                          const float* __restrict__ be0,
                                                          float* __restrict__ stats) {
    char* lds = dynsmem;
    int tid = threadIdx.x;
    int lane = tid & 63;
    int w = tid >> 6;
    int g = blockIdx.x * 4 + w;  // 0..4095
    for (int idx = tid; idx < 8192; idx += 256) {
        int o = idx >> 6, c = idx & 63;
        unsigned short hi, lo;
        bf16_split(W1[idx], hi, lo);
        int byt = (c * 2) ^ ((o & 7) << 4);
        *(unsigned short*)(lds + o * 128 + byt) = hi;
        *(unsigned short*)(lds + 16384 + o * 128 + byt) = lo;
    }
    float w0r[6];
#pragma unroll
    for (int j = 0; j < 6; ++j) w0r[j] = W0[lane * 6 + j];
    float b0v = b0[lane];
    float a0, c0v;
    bn0_from_moments(stats, g0, be0, w0r, b0v, lane, a0, c0v);
    char* X = lds + 32768 + w * 16384;  // hi @0, lo @8192
    __syncthreads();  // W1 staged
    const float* fb = feat + (size_t)g * 64 * 6;
#pragma unroll 4
    for (int r = 0; r < 64; ++r) {
        const float* f = fb + r * 6;
        float h = b0v;
#pragma unroll
        for (int j = 0; j < 6; ++j) h = fmaf(w0r[j], f[j], h);
        float hn = fmaxf(fmaf(a0, h, c0v), 0.f);
        unsigned short hi, lo;
        bf16_split(hn, hi, lo);
        int byt = (lane * 2) ^ ((r & 7) << 4);
        *(unsigned short*)(X + r * 128 + byt) = hi;
        *(unsigned short*)(X + 8192 + r * 128 + byt) = lo;
    }
    __syncthreads();  // X + W1 visible
    float b1v[8];
#pragma unroll
    for (int tn = 0; tn < 8; ++tn) b1v[tn] = b1[tn * 16 + (lane & 15)];
    float ssum[8], ssq[8];
#pragma unroll
    for (int tn = 0; tn < 8; ++tn) { ssum[tn] = 0.f; ssq[tn] = 0.f; }
#pragma unroll
    for (int tm = 0; tm < 4; ++tm) {
        bfv8 Ah[2], Al[2];
#pragma unroll
        for (int tk = 0; tk < 2; ++tk) {
            int r = tm * 16 + (lane & 15);
            int colb = (((lane >> 4) * 16) + tk * 64) ^ ((r & 7) << 4);
            Ah[tk] = *(const bfv8*)(X + r * 128 + colb);
            Al[tk] = *(const bfv8*)(X + 8192 + r * 128 + colb);
        }
#pragma unroll
        for (int tn = 0; tn < 8; ++tn) {
            int o = tn * 16 + (lane & 15);
            f32x4 acc = {0.f, 0.f, 0.f, 0.f};
#pragma unroll
            for (int tk = 0; tk < 2; ++tk) {
                int colb = (((lane >> 4) * 16) + tk * 64) ^ ((o & 7) << 4);
                bfv8 Bh = *(const bfv8*)(lds + o * 128 + colb);
                bfv8 Bl = *(const bfv8*)(lds + 16384 + o * 128 + colb);
                acc = __builtin_amdgcn_mfma_f32_16x16x32_bf16(Ah[tk], Bh, acc, 0, 0, 0);
                acc = __builtin_amdgcn_mfma_f32_16x16x32_bf16(Ah[tk], Bl, acc, 0, 0, 0);
                acc = __builtin_amdgcn_mfma_f32_16x16x32_bf16(Al[tk], Bh, acc, 0, 0, 0);
            }
#pragma unroll
            for (int j = 0; j < 4; ++j) {
                float h1 = acc[j] + b1v[tn];
                ssum[tn] += h1;
                ssq[tn] = fmaf(h1, h1, ssq[tn]);
            }
        }
    }
#pragma unroll
    for (int tn = 0; tn < 8; ++tn) {
        ssum[tn] += __shfl_xor(ssum[tn], 16);
        ssum[tn] += __shfl_xor(ssum[tn], 32);
        ssq[tn] += __shfl_xor(ssq[tn], 16);
        ssq[tn] += __shfl_xor(ssq[tn], 32);
    }
    __syncthreads();  // all GEMM LDS reads done; reuse X region for partials
    float* psum = (float*)(lds + 32768);          // [4][256]
    float* psq  = (float*)(lds + 32768 + 4096);   // [4][256]
    if (lane < 16) {
#pragma unroll
        for (int tn = 0; tn < 8; ++tn) {
            psum[w * 256 + tn * 16 + lane] = ssum[tn];
            psq[w * 256 + tn * 16 + lane] = ssq[tn];
        }
    }
    __syncthreads();
    if (tid < 128) {
        int ch = tid;
        float s = psum[ch] + psum[256 + ch] + psum[512 + ch] + psum[768 + ch];
        float q = psq[ch] + psq[256 + ch] + psq[512 + ch] + psq[768 + ch];
        atomicAdd(&stats[128 + ch], s);
        atomicAdd(&stats[256 + ch], q);
    }
}

// ---------------- Final: MFMA bf16-split GEMM + BN + maxpool ----------------
__global__ __launch_bounds__(256) void final_mfma_kernel(const float* __restrict__ feat,
                                                         const float* __restrict__ W0,
                                                         const float* __restrict__ b0,
                                                         const float* __restrict__ W1,
                                                         const float* __restrict__ b1,
                                                         const float* __restrict__ g0,
                                                         const float* __restrict__ be0,
                                                         const float* __restrict__ g1,
                                                         const float* __restrict__ be1,
                                                         const float* __restrict__ stats,
                                                         float* __restrict__ out) {
    char* lds = dynsmem;
    int tid = threadIdx.x;
    int lane = tid & 63;
    int w = tid >> 6;
    int g = blockIdx.x * 4 + w;  // 0..4095
    for (int idx = tid; idx < 8192; idx += 256) {
        int o = idx >> 6, c = idx & 63;
        unsigned short hi, lo;
        bf16_split(W1[idx], hi, lo);
        int byt = (c * 2) ^ ((o & 7) << 4);
        *(unsigned short*)(lds + o * 128 + byt) = hi;
        *(unsigned short*)(lds + 16384 + o * 128 + byt) = lo;
    }
    float w0r[6];
#pragma unroll
    for (int j = 0; j < 6; ++j) w0r[j] = W0[lane * 6 + j];
    float b0v = b0[lane];
    float a0, c0v;
    bn0_from_moments(stats, g0, be0, w0r, b0v, lane, a0, c0v);
    char* X = lds + 32768 + w * 16384;
    __syncthreads();
    const float* fb = feat + (size_t)g * 64 * 6;
#pragma unroll 4
    for (int r = 0; r < 64; ++r) {
        const float* f = fb + r * 6;
        float h = b0v;
#pragma unroll
        for (int j = 0; j < 6; ++j) h = fmaf(w0r[j], f[j], h);
        float hn = fmaxf(fmaf(a0, h, c0v), 0.f);
        unsigned short hi, lo;
        bf16_split(hn, hi, lo);
        int byt = (lane * 2) ^ ((r & 7) << 4);
        *(unsigned short*)(X + r * 128 + byt) = hi;
        *(unsigned short*)(X + 8192 + r * 128 + byt) = lo;
    }
    __syncthreads();
    // BN1 inline from raw stats1 sums
    const float inv = 1.0f / (float)MTOT;
    float a1v[8], d1v[8];
#pragma unroll
    for (int tn = 0; tn < 8; ++tn) {
        int o = tn * 16 + (lane & 15);
        float mu1 = stats[128 + o] * inv;
        float var1 = fmaxf(stats[256 + o] * inv - mu1 * mu1, 0.f);
        float a1 = g1[o] * rsqrtf(var1 + 1e-5f);
        float c1 = fmaf(-mu1, a1, be1[o]);
        a1v[tn] = a1;
        d1v[tn] = fmaf(a1, b1[o], c1);  // a1*b1 + c1
    }
    float mx[8];
#pragma unroll
    for (int tn = 0; tn < 8; ++tn) mx[tn] = -1e30f;
#pragma unroll
    for (int tm = 0; tm < 4; ++tm) {
        bfv8 Ah[2], Al[2];
#pragma unroll
        for (int tk = 0; tk < 2; ++tk) {
            int r = tm * 16 + (lane & 15);
            int colb = (((lane >> 4) * 16) + tk * 64) ^ ((r & 7) << 4);
            Ah[tk] = *(const bfv8*)(X + r * 128 + colb);
            Al[tk] = *(const bfv8*)(X + 8192 + r * 128 + colb);
        }
#pragma unroll
        for (int tn = 0; tn < 8; ++tn) {
            int o = tn * 16 + (lane & 15);
            f32x4 acc = {0.f, 0.f, 0.f, 0.f};
#pragma unroll
            for (int tk = 0; tk < 2; ++tk) {
                int colb = (((lane >> 4) * 16) + tk * 64) ^ ((o & 7) << 4);
                bfv8 Bh = *(const bfv8*)(lds + o * 128 + colb);
                bfv8 Bl = *(const bfv8*)(lds + 16384 + o * 128 + colb);
                acc = __builtin_amdgcn_mfma_f32_16x16x32_bf16(Ah[tk], Bh, acc, 0, 0, 0);
                acc = __builtin_amdgcn_mfma_f32_16x16x32_bf16(Ah[tk], Bl, acc, 0, 0, 0);
                acc = __builtin_amdgcn_mfma_f32_16x16x32_bf16(Al[tk], Bh, acc, 0, 0, 0);
            }
            float t0 = fmaxf(fmaf(a1v[tn], acc[0], d1v[tn]), 0.f);
            float t1 = fmaxf(fmaf(a1v[tn], acc[1], d1v[tn]), 0.f);
            float t2 = fmaxf(fmaf(a1v[tn], acc[2], d1v[tn]), 0.f);
            float t3 = fmaxf(fmaf(a1v[tn], acc[3], d1v[tn]), 0.f);
            mx[tn] = fmaxf(mx[tn], fmaxf(fmaxf(t0, t1), fmaxf(t2, t3)));
        }
    }
#pragma unroll
    for (int tn = 0; tn < 8; ++tn) {
        float v = mx[tn];
        v = fmaxf(v, __shfl_xor(v, 16));
        v = fmaxf(v, __shfl_xor(v, 32));
        mx[tn] = v;
    }
    if (lane < 16) {
        size_t ob = 12288 + (size_t)g * 128;
#pragma unroll
        for (int tn = 0; tn < 8; ++tn) out[ob + tn * 16 + lane] = mx[tn];
    }
}

extern "C" void kernel_launch(void* const* d_in, const int* in_sizes, int n_in,
                              void* d_out, int out_size, void* d_ws, size_t ws_size,
                              hipStream_t stream) {
    const float* xyz = (const float*)d_in[0];
    const float* pts = (const float*)d_in[1];
    const float* W0  = (const float*)d_in[2];
    const float* b0  = (const float*)d_in[3];
    const float* g0  = (const float*)d_in[4];
    const float* be0 = (const float*)d_in[5];
    const float* W1  = (const float*)d_in[6];
    const float* b1  = (const float*)d_in[7];
    const float* g1  = (const float*)d_in[8];
    const float* be1 = (const float*)d_in[9];
    float* out = (float*)d_out;

    float* feat  = (float*)d_ws;                     // 262144*6 floats = 6.29 MB
    float* stats = feat + (size_t)MTOT * 6;          // 768 floats

    const int fps_lds = 2 * NPTS * (int)sizeof(float);  // 131072
    (void)hipFuncSetAttribute(reinterpret_cast<const void*>(fps_kernel),
                              hipFuncAttributeMaxDynamicSharedMemorySize, fps_lds);
    const int fm_lds = 98304;  // 32K W1 + 4x16K X
    (void)hipFuncSetAttribute(reinterpret_cast<const void*>(stats1_mfma_kernel),
                              hipFuncAttributeMaxDynamicSharedMemorySize, fm_lds);
    (void)hipFuncSetAttribute(reinterpret_cast<const void*>(final_mfma_kernel),
                              hipFuncAttributeMaxDynamicSharedMemorySize, fm_lds);

    fps_kernel<<<NB, 1024, fps_lds, stream>>>(xyz, out, stats);
    ballq_kernel<<<1024, 256, 0, stream>>>(xyz, pts, out, feat, stats);
    stats1_mfma_kernel<<<1024, 256, fm_lds, stream>>>(feat, W0, b0, W1, b1, g0, be0, stats);
    final_mfma_kernel<<<1024, 256, fm_lds, stream>>>(feat, W0, b0, W1, b1, g0, be0, g1, be1, stats, out);
}

// Round 16
// 932.294 us; speedup vs baseline: 3.5965x; 1.0127x over previous
//
#include <hip/hip_runtime.h>

#define NB    8
#define NPTS  16384
#define NS    512
#define NK    64
#define C1    64
#define C2    128
#define RAD2  0.25f
#define MTOT  (NB*NS*NK)   // 262144 rows
// ws: feat (6.29MB) | stats (768 f)
// stats: [0:6) m_j=sum f_j | [6:27) M_jk=sum f_j f_k (j<=k, row-major upper)
//        [128:256) s1sum | [256:384) s1sq

typedef float v2f __attribute__((ext_vector_type(2)));
typedef __bf16 bfv8 __attribute__((ext_vector_type(8)));   // MFMA A/B fragment
typedef float f32x4 __attribute__((ext_vector_type(4)));

extern __shared__ char dynsmem[];   // single TU-wide dynamic-LDS symbol

// u32 max/min reduce steps via DPP (positive floats compare as u32).
#define UMAX_DPP(x, CTRL, RM)                                                   \
    do {                                                                        \
        unsigned _m = (unsigned)__builtin_amdgcn_update_dpp((int)(x), (int)(x), \
                                                            CTRL, RM, 0xf, false); \
        x = (x > _m) ? x : _m;                                                  \
    } while (0)
#define UMIN_DPP(x, CTRL, RM)                                                   \
    do {                                                                        \
        unsigned _m = (unsigned)__builtin_amdgcn_update_dpp((int)(x), (int)(x), \
                                                            CTRL, RM, 0xf, false); \
        x = (x < _m) ? x : _m;                                                  \
    } while (0)
// f32 wave-sum step (identity 0 for masked rows); total lands in lane 63.
#define FSUM_DPP(x, CTRL, RM)                                                   \
    do {                                                                        \
        int _b = __builtin_amdgcn_update_dpp(0, __float_as_int(x), CTRL, RM,    \
                                             0xf, false);                       \
        x += __int_as_float(_b);                                                \
    } while (0)

// ---------------- FPS: bit-exact farthest point sampling ----------------
// 1024 threads x 16 points (8 float2 pairs), ALL coordinates in registers
// (pxp/pyp/pzp/ddp = 64 floats + temps ~= 90 VGPR, fits the 128/wave budget
// at 16 waves/CU) -> zero DS ops in the scan. Value-only scan (contract off,
// bit-exact); wave+block u32-max DPP reduce; candidate-only index discovery;
// 2 barriers/iter; stats zeroing folded into block 0.
__global__ __launch_bounds__(1024, 4)
void fps_kernel(const float* __restrict__ xyz, float* __restrict__ out,
                float* __restrict__ stats) {
#pragma clang fp contract(off)
    int b = blockIdx.x;
    int tid = threadIdx.x;
    int lane = tid & 63;
    int w = tid >> 6;  // 16 waves
    if (b == 0 && tid < 384) stats[tid] = 0.f;  // replaces hipMemsetAsync
    const float* base = xyz + (size_t)b * NPTS * 3;
    __shared__ unsigned svals[2][16];  // per-wave max value bits, dbuf
    __shared__ unsigned sidxs[2][16];  // per-wave min candidate idx, dbuf
    v2f pxp[8], pyp[8], pzp[8], ddp[8];
#pragma unroll
    for (int jj = 0; jj < 8; ++jj) {
        int p0 = tid + (jj << 11);          // pair: (p0, p0+1024)
        int p1 = p0 + 1024;
        pxp[jj].x = base[p0 * 3 + 0]; pxp[jj].y = base[p1 * 3 + 0];
        pyp[jj].x = base[p0 * 3 + 1]; pyp[jj].y = base[p1 * 3 + 1];
        pzp[jj].x = base[p0 * 3 + 2]; pzp[jj].y = base[p1 * 3 + 2];
        ddp[jj].x = 1e10f; ddp[jj].y = 1e10f;
    }
    // iteration 0: centroid is point 0
    float cx = base[0], cy = base[1], cz = base[2];
    if (tid == 0) {
        float* o = out + (size_t)b * NS * 3;
        o[0] = cx; o[1] = cy; o[2] = cz;
    }
    __syncthreads();
    for (int i = 1; i < NS; ++i) {
        v2f cx2; cx2.x = cx; cx2.y = cx;
        v2f cy2; cy2.x = cy; cy2.y = cy;
        v2f cz2; cz2.x = cz; cz2.y = cz;
        // value-only scan; 4 independent packed max chains; pure-register
        v2f cm0, cm1, cm2, cm3;
        cm0.x = -1.f; cm0.y = -1.f; cm1 = cm0; cm2 = cm0; cm3 = cm0;
#pragma unroll
        for (int jj = 0; jj < 8; ++jj) {
            // bit-exact: contract(off) -> separate rn mul/add, order ((x2+y2)+z2)
            v2f dx = pxp[jj] - cx2;
            v2f dy = pyp[jj] - cy2;
            v2f dz = pzp[jj] - cz2;
            v2f d = (dx * dx + dy * dy) + dz * dz;
            v2f nd;
            nd.x = fminf(ddp[jj].x, d.x);
            nd.y = fminf(ddp[jj].y, d.y);
            ddp[jj] = nd;
            if ((jj & 3) == 0) { cm0.x = fmaxf(cm0.x, nd.x); cm0.y = fmaxf(cm0.y, nd.y); }
            if ((jj & 3) == 1) { cm1.x = fmaxf(cm1.x, nd.x); cm1.y = fmaxf(cm1.y, nd.y); }
            if ((jj & 3) == 2) { cm2.x = fmaxf(cm2.x, nd.x); cm2.y = fmaxf(cm2.y, nd.y); }
            if ((jj & 3) == 3) { cm3.x = fmaxf(cm3.x, nd.x); cm3.y = fmaxf(cm3.y, nd.y); }
        }
        v2f m01; m01.x = fmaxf(cm0.x, cm1.x); m01.y = fmaxf(cm0.y, cm1.y);
        v2f m23; m23.x = fmaxf(cm2.x, cm3.x); m23.y = fmaxf(cm2.y, cm3.y);
        float bv = fmaxf(fmaxf(m01.x, m23.x), fmaxf(m01.y, m23.y));  // thread max (exact)
        // wave(64) value max via DPP on u32 bits (positive floats)
        unsigned vb = (unsigned)__float_as_int(bv);
        UMAX_DPP(vb, 0xB1, 0xf);   // quad_perm xor1
        UMAX_DPP(vb, 0x4E, 0xf);   // quad_perm xor2
        UMAX_DPP(vb, 0x141, 0xf);  // row_half_mirror
        UMAX_DPP(vb, 0x140, 0xf);  // row_mirror
        UMAX_DPP(vb, 0x142, 0xa);  // row_bcast15
        UMAX_DPP(vb, 0x143, 0xc);  // row_bcast31
        if (lane == 63) svals[i & 1][w] = vb;
        __syncthreads();           // barrier 1: wave maxes visible
        unsigned wv = svals[i & 1][lane & 15];
        UMAX_DPP(wv, 0xB1, 0xf);
        UMAX_DPP(wv, 0x4E, 0xf);
        UMAX_DPP(wv, 0x141, 0xf);
        UMAX_DPP(wv, 0x140, 0xf);
        float W = __int_as_float((int)wv);  // exact block max, uniform
        // index discovery + UMIN chain: only candidate wave(s) pay for it
        unsigned lidx = 0x7fffffffu;
        if (__any(bv == W)) {
#pragma unroll
            for (int jj = 7; jj >= 0; --jj) {  // descending -> lowest idx wins
                if (ddp[jj].y == W) lidx = (unsigned)(tid + (jj << 11) + 1024);
                if (ddp[jj].x == W) lidx = (unsigned)(tid + (jj << 11));
            }
            UMIN_DPP(lidx, 0xB1, 0xf);
            UMIN_DPP(lidx, 0x4E, 0xf);
            UMIN_DPP(lidx, 0x141, 0xf);
            UMIN_DPP(lidx, 0x140, 0xf);
            UMIN_DPP(lidx, 0x142, 0xa);
            UMIN_DPP(lidx, 0x143, 0xc);
        }
        if (lane == 63) sidxs[i & 1][w] = lidx;  // non-candidates: identity
        __syncthreads();           // barrier 2: candidate indices visible
        unsigned ci = sidxs[i & 1][lane & 15];
        UMIN_DPP(ci, 0xB1, 0xf);
        UMIN_DPP(ci, 0x4E, 0xf);
        UMIN_DPP(ci, 0x141, 0xf);
        UMIN_DPP(ci, 0x140, 0xf);
        int ii = __builtin_amdgcn_readfirstlane((int)ci);  // uniform winner
        const float* cp = base + (size_t)ii * 3;
        cx = cp[0]; cy = cp[1]; cz = cp[2];
        if (tid == 0) {
            float* o = out + ((size_t)b * NS + i) * 3;
            o[0] = cx; o[1] = cy; o[2] = cz;
        }
    }
}

// --- Ball query + gather + FUSED layer-0 moment accumulation ---
__global__ __launch_bounds__(256) void ballq_kernel(const float* __restrict__ xyz,
                                                    const float* __restrict__ pts,
                                                    const float* __restrict__ newxyz,
                                                    float* __restrict__ feat,
                                                    float* __restrict__ stats) {
    int w = threadIdx.x >> 6;
    int lane = threadIdx.x & 63;
    int wid = blockIdx.x * 4 + w;   // 0..4095 == b*512+s
    int b = wid >> 9;
    const float* nx = newxyz + (size_t)wid * 3;
    float cx = nx[0], cy = nx[1], cz = nx[2];
    float sa = __fadd_rn(__fadd_rn(__fmul_rn(cx, cx), __fmul_rn(cy, cy)),
                         __fmul_rn(cz, cz));
    __shared__ int sidx[4][64];
    __shared__ float pm[4][27];
    const float* base = xyz + (size_t)b * NPTS * 3;
    int cnt = 0;
    for (int off = 0; off < NPTS && cnt < NK; off += 64) {
        int p = off + lane;
        float bx = base[p * 3 + 0], by = base[p * 3 + 1], bz = base[p * 3 + 2];
        float sb = __fadd_rn(__fadd_rn(__fmul_rn(bx, bx), __fmul_rn(by, by)),
                             __fmul_rn(bz, bz));
        float dt = __fadd_rn(__fadd_rn(__fmul_rn(cx, bx), __fmul_rn(cy, by)),
                             __fmul_rn(cz, bz));
        float sq = __fsub_rn(__fadd_rn(sa, sb), __fmul_rn(2.0f, dt));
        bool inb = !(sq > RAD2);           // strict >, matches reference
        unsigned long long mask = __ballot(inb);
        int pos = cnt + (int)__popcll(mask & ((1ull << lane) - 1ull));
        if (inb && pos < NK) sidx[w][pos] = p;
        cnt += (int)__popcll(mask);
    }
    __syncthreads();
    int filled = cnt < NK ? cnt : NK;
    int sel = (lane < filled) ? lane : 0;
    int p = (filled > 0) ? sidx[w][sel] : 0;  // filled>0 always (self in radius)
    float gx = base[p * 3 + 0], gy = base[p * 3 + 1], gz = base[p * 3 + 2];
    const float* pb = pts + (size_t)b * NPTS * 3;
    float rowf[6];
    rowf[0] = __fsub_rn(gx, cx);
    rowf[1] = __fsub_rn(gy, cy);
    rowf[2] = __fsub_rn(gz, cz);
    rowf[3] = pb[p * 3 + 0];
    rowf[4] = pb[p * 3 + 1];
    rowf[5] = pb[p * 3 + 2];
    float* fr = feat + ((size_t)wid * NK + lane) * 6;
#pragma unroll
    for (int j = 0; j < 6; ++j) fr[j] = rowf[j];
    // 27 moments of this lane's row
    float mom[27];
#pragma unroll
    for (int j = 0; j < 6; ++j) mom[j] = rowf[j];
    {
        int t = 6;
#pragma unroll
        for (int j = 0; j < 6; ++j)
#pragma unroll
            for (int k = j; k < 6; ++k) mom[t++] = rowf[j] * rowf[k];
    }
#pragma unroll
    for (int t = 0; t < 27; ++t) {
        FSUM_DPP(mom[t], 0xB1, 0xf);
        FSUM_DPP(mom[t], 0x4E, 0xf);
        FSUM_DPP(mom[t], 0x141, 0xf);
        FSUM_DPP(mom[t], 0x140, 0xf);
        FSUM_DPP(mom[t], 0x142, 0xa);
        FSUM_DPP(mom[t], 0x143, 0xc);
        if (lane == 63) pm[w][t] = mom[t];  // wave total in lane 63
    }
    __syncthreads();
    if (threadIdx.x < 27) {
        int t = threadIdx.x;
        float s = pm[0][t] + pm[1][t] + pm[2][t] + pm[3][t];
        atomicAdd(&stats[t], s);
    }
}

// helper: split f32 -> (hi, lo) round-to-nearest bf16 pair
__device__ __forceinline__ void bf16_split(float v, unsigned short& hi, unsigned short& lo) {
    unsigned u = __float_as_uint(v);
    unsigned h = (u + 0x7fffu + ((u >> 16) & 1u)) >> 16;
    float rem = v - __uint_as_float(h << 16);
    unsigned ur = __float_as_uint(rem);
    unsigned l = (ur + 0x7fffu + ((ur >> 16) & 1u)) >> 16;
    hi = (unsigned short)h; lo = (unsigned short)l;
}

// BN0 params for channel c (= lane) from the 27 global moments.
// Identical expression in stats1_mfma and final_mfma -> identical h0n.
__device__ __forceinline__ void bn0_from_moments(const float* __restrict__ stats,
                                                 const float* __restrict__ g0,
                                                 const float* __restrict__ be0,
                                                 const float* w0r, float b0v,
                                                 int lane, float& a0, float& c0v) {
    const float inv = 1.0f / (float)MTOT;
    float m6[6];
#pragma unroll
    for (int j = 0; j < 6; ++j) m6[j] = stats[j];
    float s = 0.f;
#pragma unroll
    for (int j = 0; j < 6; ++j) s = fmaf(w0r[j], m6[j], s);
    float quad = 0.f;
    {
        int t = 6;
#pragma unroll
        for (int j = 0; j < 6; ++j)
#pragma unroll
            for (int k = j; k < 6; ++k) {
                float coef = w0r[j] * w0r[k];
                if (j != k) coef = coef + coef;
                quad = fmaf(coef, stats[t], quad);
                ++t;
            }
    }
    float mu0 = fmaf(s, inv, b0v);
    float e2 = fmaf(quad, inv, fmaf(2.f * b0v * s, inv, b0v * b0v));
    float var0 = fmaxf(e2 - mu0 * mu0, 0.f);
    a0 = g0[lane] * rsqrtf(var0 + 1e-5f);
    c0v = fmaf(-mu0, a0, be0[lane]);
}

// ---------------- Layer-1 stats via MFMA bf16-split GEMM ----------------
__global__ __launch_bounds__(256) void stats1_mfma_kernel(const float* __restrict__ feat,
                                                          const float* __restrict__ W0,
                                                          const float* __restrict__ b0,
                                                          const float* __restrict__ W1,
                                                          const float* __restrict__ b1,
                                                          const float* __restrict__ g0,
                                                          const float* __restrict__ be0,
                                                          float* __restrict__ stats) {
    char* lds = dynsmem;
    int tid = threadIdx.x;
    int lane = tid & 63;
    int w = tid >> 6;
    int g = blockIdx.x * 4 + w;  // 0..4095
    for (int idx = tid; idx < 8192; idx += 256) {
        int o = idx >> 6, c = idx & 63;
        unsigned short hi, lo;
        bf16_split(W1[idx], hi, lo);
        int byt = (c * 2) ^ ((o & 7) << 4);
        *(unsigned short*)(lds + o * 128 + byt) = hi;
        *(unsigned short*)(lds + 16384 + o * 128 + byt) = lo;
    }
    float w0r[6];
#pragma unroll
    for (int j = 0; j < 6; ++j) w0r[j] = W0[lane * 6 + j];
    float b0v = b0[lane];
    float a0, c0v;
    bn0_from_moments(stats, g0, be0, w0r, b0v, lane, a0, c0v);
    char* X = lds + 32768 + w * 16384;  // hi @0, lo @8192
    __syncthreads();  // W1 staged
    const float* fb = feat + (size_t)g * 64 * 6;
#pragma unroll 4
    for (int r = 0; r < 64; ++r) {
        const float* f = fb + r * 6;
        float h = b0v;
#pragma unroll
        for (int j = 0; j < 6; ++j) h = fmaf(w0r[j], f[j], h);
        float hn = fmaxf(fmaf(a0, h, c0v), 0.f);
        unsigned short hi, lo;
        bf16_split(hn, hi, lo);
        int byt = (lane * 2) ^ ((r & 7) << 4);
        *(unsigned short*)(X + r * 128 + byt) = hi;
        *(unsigned short*)(X + 8192 + r * 128 + byt) = lo;
    }
    __syncthreads();  // X + W1 visible
    float b1v[8];
#pragma unroll
    for (int tn = 0; tn < 8; ++tn) b1v[tn] = b1[tn * 16 + (lane & 15)];
    float ssum[8], ssq[8];
#pragma unroll
    for (int tn = 0; tn < 8; ++tn) { ssum[tn] = 0.f; ssq[tn] = 0.f; }
#pragma unroll
    for (int tm = 0; tm < 4; ++tm) {
        bfv8 Ah[2], Al[2];
#pragma unroll
        for (int tk = 0; tk < 2; ++tk) {
            int r = tm * 16 + (lane & 15);
            int colb = (((lane >> 4) * 16) + tk * 64) ^ ((r & 7) << 4);
            Ah[tk] = *(const bfv8*)(X + r * 128 + colb);
            Al[tk] = *(const bfv8*)(X + 8192 + r * 128 + colb);
        }
#pragma unroll
        for (int tn = 0; tn < 8; ++tn) {
            int o = tn * 16 + (lane & 15);
            f32x4 acc = {0.f, 0.f, 0.f, 0.f};
#pragma unroll
            for (int tk = 0; tk < 2; ++tk) {
                int colb = (((lane >> 4) * 16) + tk * 64) ^ ((o & 7) << 4);
                bfv8 Bh = *(const bfv8*)(lds + o * 128 + colb);
                bfv8 Bl = *(const bfv8*)(lds + 16384 + o * 128 + colb);
                acc = __builtin_amdgcn_mfma_f32_16x16x32_bf16(Ah[tk], Bh, acc, 0, 0, 0);
                acc = __builtin_amdgcn_mfma_f32_16x16x32_bf16(Ah[tk], Bl, acc, 0, 0, 0);
                acc = __builtin_amdgcn_mfma_f32_16x16x32_bf16(Al[tk], Bh, acc, 0, 0, 0);
            }
#pragma unroll
            for (int j = 0; j < 4; ++j) {
                float h1 = acc[j] + b1v[tn];
                ssum[tn] += h1;
                ssq[tn] = fmaf(h1, h1, ssq[tn]);
            }
        }
    }
#pragma unroll
    for (int tn = 0; tn < 8; ++tn) {
        ssum[tn] += __shfl_xor(ssum[tn], 16);
        ssum[tn] += __shfl_xor(ssum[tn], 32);
        ssq[tn] += __shfl_xor(ssq[tn], 16);
        ssq[tn] += __shfl_xor(ssq[tn], 32);
    }
    __syncthreads();  // all GEMM LDS reads done; reuse X region for partials
    float* psum = (float*)(lds + 32768);          // [4][256]
    float* psq  = (float*)(lds + 32768 + 4096);   // [4][256]
    if (lane < 16) {
#pragma unroll
        for (int tn = 0; tn < 8; ++tn) {
            psum[w * 256 + tn * 16 + lane] = ssum[tn];
            psq[w * 256 + tn * 16 + lane] = ssq[tn];
        }
    }
    __syncthreads();
    if (tid < 128) {
        int ch = tid;
        float s = psum[ch] + psum[256 + ch] + psum[512 + ch] + psum[768 + ch];
        float q = psq[ch] + psq[256 + ch] + psq[512 + ch] + psq[768 + ch];
        atomicAdd(&stats[128 + ch], s);
        atomicAdd(&stats[256 + ch], q);
    }
}

// ---------------- Final: MFMA bf16-split GEMM + BN + maxpool ----------------
__global__ __launch_bounds__(256) void final_mfma_kernel(const float* __restrict__ feat,
                                                         const float* __restrict__ W0,
                                                         const float* __restrict__ b0,
                                                         const float* __restrict__ W1,
                                                         const float* __restrict__ b1,
                                                         const float* __restrict__ g0,
                                                         const float* __restrict__ be0,
                                                         const float* __restrict__ g1,
                                                         const float* __restrict__ be1,
                                                         const float* __restrict__ stats,
                                                         float* __restrict__ out) {
    char* lds = dynsmem;
    int tid = threadIdx.x;
    int lane = tid & 63;
    int w = tid >> 6;
    int g = blockIdx.x * 4 + w;  // 0..4095
    for (int idx = tid; idx < 8192; idx += 256) {
        int o = idx >> 6, c = idx & 63;
        unsigned short hi, lo;
        bf16_split(W1[idx], hi, lo);
        int byt = (c * 2) ^ ((o & 7) << 4);
        *(unsigned short*)(lds + o * 128 + byt) = hi;
        *(unsigned short*)(lds + 16384 + o * 128 + byt) = lo;
    }
    float w0r[6];
#pragma unroll
    for (int j = 0; j < 6; ++j) w0r[j] = W0[lane * 6 + j];
    float b0v = b0[lane];
    float a0, c0v;
    bn0_from_moments(stats, g0, be0, w0r, b0v, lane, a0, c0v);
    char* X = lds + 32768 + w * 16384;
    __syncthreads();
    const float* fb = feat + (size_t)g * 64 * 6;
#pragma unroll 4
    for (int r = 0; r < 64; ++r) {
        const float* f = fb + r * 6;
        float h = b0v;
#pragma unroll
        for (int j = 0; j < 6; ++j) h = fmaf(w0r[j], f[j], h);
        float hn = fmaxf(fmaf(a0, h, c0v), 0.f);
        unsigned short hi, lo;
        bf16_split(hn, hi, lo);
        int byt = (lane * 2) ^ ((r & 7) << 4);
        *(unsigned short*)(X + r * 128 + byt) = hi;
        *(unsigned short*)(X + 8192 + r * 128 + byt) = lo;
    }
    __syncthreads();
    // BN1 inline from raw stats1 sums
    const float inv = 1.0f / (float)MTOT;
    float a1v[8], d1v[8];
#pragma unroll
    for (int tn = 0; tn < 8; ++tn) {
        int o = tn * 16 + (lane & 15);
        float mu1 = stats[128 + o] * inv;
        float var1 = fmaxf(stats[256 + o] * inv - mu1 * mu1, 0.f);
        float a1 = g1[o] * rsqrtf(var1 + 1e-5f);
        float c1 = fmaf(-mu1, a1, be1[o]);
        a1v[tn] = a1;
        d1v[tn] = fmaf(a1, b1[o], c1);  // a1*b1 + c1
    }
    float mx[8];
#pragma unroll
    for (int tn = 0; tn < 8; ++tn) mx[tn] = -1e30f;
#pragma unroll
    for (int tm = 0; tm < 4; ++tm) {
        bfv8 Ah[2], Al[2];
#pragma unroll
        for (int tk = 0; tk < 2; ++tk) {
            int r = tm * 16 + (lane & 15);
            int colb = (((lane >> 4) * 16) + tk * 64) ^ ((r & 7) << 4);
            Ah[tk] = *(const bfv8*)(X + r * 128 + colb);
            Al[tk] = *(const bfv8*)(X + 8192 + r * 128 + colb);
        }
#pragma unroll
        for (int tn = 0; tn < 8; ++tn) {
            int o = tn * 16 + (lane & 15);
            f32x4 acc = {0.f, 0.f, 0.f, 0.f};
#pragma unroll
            for (int tk = 0; tk < 2; ++tk) {
                int colb = (((lane >> 4) * 16) + tk * 64) ^ ((o & 7) << 4);
                bfv8 Bh = *(const bfv8*)(lds + o * 128 + colb);
                bfv8 Bl = *(const bfv8*)(lds + 16384 + o * 128 + colb);
                acc = __builtin_amdgcn_mfma_f32_16x16x32_bf16(Ah[tk], Bh, acc, 0, 0, 0);
                acc = __builtin_amdgcn_mfma_f32_16x16x32_bf16(Ah[tk], Bl, acc, 0, 0, 0);
                acc = __builtin_amdgcn_mfma_f32_16x16x32_bf16(Al[tk], Bh, acc, 0, 0, 0);
            }
            float t0 = fmaxf(fmaf(a1v[tn], acc[0], d1v[tn]), 0.f);
            float t1 = fmaxf(fmaf(a1v[tn], acc[1], d1v[tn]), 0.f);
            float t2 = fmaxf(fmaf(a1v[tn], acc[2], d1v[tn]), 0.f);
            float t3 = fmaxf(fmaf(a1v[tn], acc[3], d1v[tn]), 0.f);
            mx[tn] = fmaxf(mx[tn], fmaxf(fmaxf(t0, t1), fmaxf(t2, t3)));
        }
    }
#pragma unroll
    for (int tn = 0; tn < 8; ++tn) {
        float v = mx[tn];
        v = fmaxf(v, __shfl_xor(v, 16));
        v = fmaxf(v, __shfl_xor(v, 32));
        mx[tn] = v;
    }
    if (lane < 16) {
        size_t ob = 12288 + (size_t)g * 128;
#pragma unroll
        for (int tn = 0; tn < 8; ++tn) out[ob + tn * 16 + lane] = mx[tn];
    }
}

extern "C" void kernel_launch(void* const* d_in, const int* in_sizes, int n_in,
                              void* d_out, int out_size, void* d_ws, size_t ws_size,
                              hipStream_t stream) {
    const float* xyz = (const float*)d_in[0];
    const float* pts = (const float*)d_in[1];
    const float* W0  = (const float*)d_in[2];
    const float* b0  = (const float*)d_in[3];
    const float* g0  = (const float*)d_in[4];
    const float* be0 = (const float*)d_in[5];
    const float* W1  = (const float*)d_in[6];
    const float* b1  = (const float*)d_in[7];
    const float* g1  = (const float*)d_in[8];
    const float* be1 = (const float*)d_in[9];
    float* out = (float*)d_out;

    float* feat  = (float*)d_ws;                     // 262144*6 floats = 6.29 MB
    float* stats = feat + (size_t)MTOT * 6;          // 768 floats

    const int fm_lds = 98304;  // 32K W1 + 4x16K X
    (void)hipFuncSetAttribute(reinterpret_cast<const void*>(stats1_mfma_kernel),
                              hipFuncAttributeMaxDynamicSharedMemorySize, fm_lds);
    (void)hipFuncSetAttribute(reinterpret_cast<const void*>(final_mfma_kernel),
                              hipFuncAttributeMaxDynamicSharedMemorySize, fm_lds);

    fps_kernel<<<NB, 1024, 0, stream>>>(xyz, out, stats);
    ballq_kernel<<<1024, 256, 0, stream>>>(xyz, pts, out, feat, stats);
    stats1_mfma_kernel<<<1024, 256, fm_lds, stream>>>(feat, W0, b0, W1, b1, g0, be0, stats);
    final_mfma_kernel<<<1024, 256, fm_lds, stream>>>(feat, W0, b0, W1, b1, g0, be0, g1, be1, stats, out);
}